// Round 3
// baseline (1498.430 us; speedup 1.0000x reference)
//
#include <hip/hip_runtime.h>
#include <cstdint>
#include <cstddef>

#define F_IN  512
#define F_HID 256
#define F_OUT 40
#define F_OUTP 48    // padded to 3x16 MFMA tiles
#define H2_LD 64     // h2 row stride in ushorts (128 B, 2 lines, aligned)

#define HBINS 16384        // 64 KB LDS histogram bins
#define HSLICES 36         // edge slices for hist/place passes

typedef short  bf16x8 __attribute__((ext_vector_type(8)));
typedef float  f32x4  __attribute__((ext_vector_type(4)));
typedef float  f32x2  __attribute__((ext_vector_type(2)));

__device__ __forceinline__ ushort f2b(float f) {   // fp32 -> bf16 RNE
    uint u = __float_as_uint(f);
    return (ushort)((u + 0x7FFFu + ((u >> 16) & 1u)) >> 16);
}
__device__ __forceinline__ uint pack2(float a, float b) {
    return (uint)f2b(a) | ((uint)f2b(b) << 16);
}
__device__ __forceinline__ float b2f(ushort u) {
    return __uint_as_float(((uint)u) << 16);
}

// ---------------------------------------------------------------------------
// Degree histogram WITHOUT global atomics: block (slice s, range r, array a)
// scans its edge slice, counts indices in [r*HBINS, r*HBINS+HBINS) into an LDS
// histogram, writes the 64 KB partial to scratch non-atomically.
// ---------------------------------------------------------------------------

__global__ __launch_bounds__(1024) void hist_kernel(const int* __restrict__ ei,
                                                    int* __restrict__ part,
                                                    int E, int NR) {
    __shared__ int hist[HBINS];
    const int tid = threadIdx.x;
    const int s = blockIdx.x;
    const int r = blockIdx.y;
    const int a = blockIdx.z;
    const int* src = ei + (size_t)a * E;   // a=0: row, a=1: col
    const uint base = (uint)r * HBINS;

    for (int i = tid; i < HBINS; i += 1024) hist[i] = 0;
    __syncthreads();

    int elen  = (E + HSLICES - 1) / HSLICES;
    int start = s * elen;
    int end   = min(start + elen, E);
    for (int i = start + tid; i < end; i += 1024) {
        uint b = (uint)src[i] - base;
        if (b < HBINS) atomicAdd(&hist[b], 1);
    }
    __syncthreads();

    int* dst = part + ((size_t)(a * NR + r) * HSLICES + s) * HBINS;
    for (int i = tid; i < HBINS; i += 1024) dst[i] = hist[i];
}

// Sum the HSLICES partials per (array, node). a=0 -> cnt_row; a=1 -> dinv.
__global__ void hist_reduce(const int* __restrict__ part,
                            int* __restrict__ cnt_row,
                            float* __restrict__ dinv, int N, int NR) {
    int t = blockIdx.x * blockDim.x + threadIdx.x;
    if (t >= 2 * N) return;
    int a = (t >= N) ? 1 : 0;
    int i = t - a * N;
    int r = i >> 14;             // / HBINS
    int bin = i & (HBINS - 1);
    const int* p = part + ((size_t)(a * NR + r) * HSLICES) * HBINS + bin;
    int sum = 0;
#pragma unroll 4
    for (int s = 0; s < HSLICES; ++s) sum += p[(size_t)s * HBINS];
    if (a == 0) cnt_row[i] = sum;
    else        dinv[i] = rsqrtf((float)(sum + 1));
}

// ---------------------------------------------------------------------------
// Single-block exclusive scan of cnt_row -> rowptr[N+1].
// ---------------------------------------------------------------------------

__global__ __launch_bounds__(1024) void scan_kernel(const int* __restrict__ cnt,
                                                    int* __restrict__ rowptr, int N) {
    __shared__ int sums[1024];
    int tid = threadIdx.x;
    int chunk = (N + 1023) >> 10;
    int s0 = tid * chunk;
    int s1 = s0 + chunk;
    if (s0 > N) s0 = N;
    if (s1 > N) s1 = N;
    int sum = 0;
    for (int i = s0; i < s1; ++i) sum += cnt[i];
    sums[tid] = sum;
    __syncthreads();
    for (int off = 1; off < 1024; off <<= 1) {
        int v = (tid >= off) ? sums[tid - off] : 0;
        __syncthreads();
        sums[tid] += v;
        __syncthreads();
    }
    int base = (tid > 0) ? sums[tid - 1] : 0;
    for (int i = s0; i < s1; ++i) {
        rowptr[i] = base;
        base += cnt[i];
    }
    if (tid == 0) rowptr[N] = sums[1023];
}

// ---------------------------------------------------------------------------
// offs[r][s][bin] = rowptr[node] + sum_{s'<s} part[a=0][r][s'][bin].
// One thread per node; per-s writes are lane-consecutive -> coalesced.
// ---------------------------------------------------------------------------

__global__ void slice_scan(const int* __restrict__ part,
                           const int* __restrict__ rowptr,
                           int* __restrict__ offs, int N, int NR) {
    int i = blockIdx.x * blockDim.x + threadIdx.x;
    if (i >= NR * HBINS) return;
    int r = i >> 14;
    int bin = i & (HBINS - 1);
    int acc = (i < N) ? rowptr[i] : 0;
    const int* p = part + ((size_t)r * HSLICES) * HBINS + bin;   // a=0 block
    int* o = offs + ((size_t)r * HSLICES) * HBINS + bin;
    for (int s = 0; s < HSLICES; ++s) {
        o[(size_t)s * HBINS] = acc;
        acc += p[(size_t)s * HBINS];
    }
}

// ---------------------------------------------------------------------------
// CSR placement with LDS cursors only (no global atomics). Block (s, r) loads
// its offset slab into LDS, re-scans its edge slice, places in-range edges.
// ---------------------------------------------------------------------------

__global__ __launch_bounds__(1024) void place_kernel(const int* __restrict__ ei,
                                                     const float* __restrict__ dinv,
                                                     const int* __restrict__ offs,
                                                     uint2* __restrict__ edge_s,
                                                     int E, int NR) {
    __shared__ int cur[HBINS];
    const int tid = threadIdx.x;
    const int s = blockIdx.x;
    const int r = blockIdx.y;
    const int* row = ei;
    const int* col = ei + E;
    const uint base = (uint)r * HBINS;
    const int* oslab = offs + ((size_t)r * HSLICES + s) * HBINS;

    for (int i = tid; i < HBINS; i += 1024) cur[i] = oslab[i];
    __syncthreads();

    int elen  = (E + HSLICES - 1) / HSLICES;
    int start = s * elen;
    int end   = min(start + elen, E);
    for (int i = start + tid; i < end; i += 1024) {
        uint b = (uint)row[i] - base;
        if (b < HBINS) {
            int pos = atomicAdd(&cur[b], 1);
            int c = col[i];
            uint2 v;
            v.x = (uint)c;
            v.y = __float_as_uint(dinv[base + b] * dinv[c]);
            edge_s[pos] = v;
        }
    }
}

// ---------------------------------------------------------------------------
// Weight prep: W1T [256][512] bf16 (= W1^T), W2T [48][256] bf16 (rows 40..47=0).
// ---------------------------------------------------------------------------

__global__ void prep_weights(const float* __restrict__ W1, const float* __restrict__ W2,
                             ushort* __restrict__ W1T, ushort* __restrict__ W2T) {
    int t = blockIdx.x * blockDim.x + threadIdx.x;
    if (t < F_HID * F_IN) {
        int n = t >> 9, k = t & 511;
        W1T[t] = f2b(W1[(size_t)k * F_HID + n]);
        return;
    }
    int u = t - F_HID * F_IN;
    if (u < F_OUTP * F_HID) {
        int n = u >> 8, k = u & 255;
        W2T[u] = f2b((n < F_OUT) ? W2[(size_t)k * F_OUT + n] : 0.f);
    }
}

// ---------------------------------------------------------------------------
// GEMM1 (MFMA bf16): h[M,256] = x[M,512] @ W1.  BM=64, BN=256, BK=32.
// Output h stored as fp8 e4m3 (256 B/row) for prop1's gathers.
// ---------------------------------------------------------------------------

#define G1_LDK 40

__global__ __launch_bounds__(256) void gemm1_mfma(const float* __restrict__ A,
                                                  const ushort* __restrict__ BT,
                                                  unsigned char* __restrict__ C, int M) {
    __shared__ ushort As[64 * G1_LDK];
    __shared__ ushort Bs[256 * G1_LDK];
    const int tid  = threadIdx.x;
    const int bm   = blockIdx.x * 64;
    const int wave = tid >> 6;
    const int lane = tid & 63;
    const int quad = lane >> 4;
    const int l16  = lane & 15;

    f32x4 acc[4][4] = {};

    const int ar = tid >> 2;
    const int ac = (tid & 3) * 8;

    for (int k0 = 0; k0 < F_IN; k0 += 32) {
        {
            int gr = bm + ar;
            float4 v0 = make_float4(0.f, 0.f, 0.f, 0.f), v1 = v0;
            if (gr < M) {
                const float* ap = A + (size_t)gr * F_IN + k0 + ac;
                v0 = *(const float4*)(ap);
                v1 = *(const float4*)(ap + 4);
            }
            uint4 w;
            w.x = pack2(v0.x, v0.y);
            w.y = pack2(v0.z, v0.w);
            w.z = pack2(v1.x, v1.y);
            w.w = pack2(v1.z, v1.w);
            *(uint4*)&As[ar * G1_LDK + ac] = w;
        }
#pragma unroll
        for (int p = 0; p < 4; ++p) {
            int idx = tid + p * 256;
            int r = idx >> 2;
            int c = (idx & 3) * 8;
            uint4 v = *(const uint4*)(BT + (size_t)r * F_IN + k0 + c);
            *(uint4*)&Bs[r * G1_LDK + c] = v;
        }
        __syncthreads();

        bf16x8 af[4], bfr[4];
#pragma unroll
        for (int mt = 0; mt < 4; ++mt)
            af[mt] = *(bf16x8*)&As[(mt * 16 + l16) * G1_LDK + quad * 8];
#pragma unroll
        for (int nt = 0; nt < 4; ++nt)
            bfr[nt] = *(bf16x8*)&Bs[(wave * 64 + nt * 16 + l16) * G1_LDK + quad * 8];
#pragma unroll
        for (int mt = 0; mt < 4; ++mt)
#pragma unroll
            for (int nt = 0; nt < 4; ++nt)
                acc[mt][nt] = __builtin_amdgcn_mfma_f32_16x16x32_bf16(af[mt], bfr[nt],
                                                                     acc[mt][nt], 0, 0, 0);
        __syncthreads();
    }

#pragma unroll
    for (int mt = 0; mt < 4; ++mt) {
#pragma unroll
        for (int i = 0; i < 4; ++i) {
            int row = bm + mt * 16 + quad * 4 + i;
            if (row < M) {
#pragma unroll
                for (int nt = 0; nt < 4; ++nt) {
                    int col = wave * 64 + nt * 16 + l16;
                    uint pk = (uint)__builtin_amdgcn_cvt_pk_fp8_f32(acc[mt][nt][i], 0.f, 0, false);
                    C[(size_t)row * F_HID + col] = (unsigned char)pk;
                }
            }
        }
    }
}

// ---------------------------------------------------------------------------
// Propagate layer 1 (F=256, fp8) + bias + ReLU. TWO edges per wave gather
// instruction: lanes 0-31 load edge A's row (8 B/lane dwordx2), lanes 32-63
// edge B's. Edge records read as aligned dwordx4 pairs. Halves vmem
// instructions/edge. Cross-half combine via shfl_xor(32).
// ---------------------------------------------------------------------------

#define P1E 16   // edges per iteration = 8 aligned pairs

__global__ __launch_bounds__(256) void prop1_kernel(const unsigned char* __restrict__ h,
                                                    const float* __restrict__ b1,
                                                    const float* __restrict__ dinv,
                                                    const int* __restrict__ rowptr,
                                                    const uint2* __restrict__ edge_s,
                                                    ushort* __restrict__ g, int N, int E) {
    int wid  = (blockIdx.x * blockDim.x + threadIdx.x) >> 6;
    int lane = threadIdx.x & 63;
    if (wid >= N) return;
    const uint2* hq = (const uint2*)h;      // row = 32 uint2 slots (256 B)
    const int half = lane >> 5;
    const int slot = lane & 31;
    float di = dinv[wid];
    float sn = (half == 0) ? di * di : 0.f;   // self term counted once (low half)

    float acc[8];
    {
        uint2 sv = hq[(size_t)wid * 32 + slot];
        f32x2 a01 = __builtin_amdgcn_cvt_pk_f32_fp8((int)sv.x, false);
        f32x2 a23 = __builtin_amdgcn_cvt_pk_f32_fp8((int)sv.x, true);
        f32x2 a45 = __builtin_amdgcn_cvt_pk_f32_fp8((int)sv.y, false);
        f32x2 a67 = __builtin_amdgcn_cvt_pk_f32_fp8((int)sv.y, true);
        acc[0] = sn * a01.x; acc[1] = sn * a01.y;
        acc[2] = sn * a23.x; acc[3] = sn * a23.y;
        acc[4] = sn * a45.x; acc[5] = sn * a45.y;
        acc[6] = sn * a67.x; acc[7] = sn * a67.y;
    }

    int e0 = rowptr[wid], e1 = rowptr[wid + 1];
    const int eE = E - 2;                    // last aligned pair start
    for (int e = (e0 & ~1); e < e1; e += P1E) {
        uint4 rec[P1E / 2];
        uint2 v[P1E / 2];
        float w[P1E / 2];
#pragma unroll
        for (int u = 0; u < P1E / 2; ++u) {
            int i0 = min(e + 2 * u, eE);     // even, 16 B aligned
            rec[u] = *(const uint4*)(edge_s + i0);
        }
#pragma unroll
        for (int u = 0; u < P1E / 2; ++u) {
            int idx = e + 2 * u + half;
            uint col = half ? rec[u].z : rec[u].x;
            uint wb  = half ? rec[u].w : rec[u].y;
            w[u] = (idx >= e0 && idx < e1) ? __uint_as_float(wb) : 0.f;
            v[u] = hq[(size_t)col * 32 + slot];
        }
#pragma unroll
        for (int u = 0; u < P1E / 2; ++u) {
            f32x2 a01 = __builtin_amdgcn_cvt_pk_f32_fp8((int)v[u].x, false);
            f32x2 a23 = __builtin_amdgcn_cvt_pk_f32_fp8((int)v[u].x, true);
            f32x2 a45 = __builtin_amdgcn_cvt_pk_f32_fp8((int)v[u].y, false);
            f32x2 a67 = __builtin_amdgcn_cvt_pk_f32_fp8((int)v[u].y, true);
            acc[0] = fmaf(w[u], a01.x, acc[0]); acc[1] = fmaf(w[u], a01.y, acc[1]);
            acc[2] = fmaf(w[u], a23.x, acc[2]); acc[3] = fmaf(w[u], a23.y, acc[3]);
            acc[4] = fmaf(w[u], a45.x, acc[4]); acc[5] = fmaf(w[u], a45.y, acc[5]);
            acc[6] = fmaf(w[u], a67.x, acc[6]); acc[7] = fmaf(w[u], a67.y, acc[7]);
        }
    }

#pragma unroll
    for (int j = 0; j < 8; ++j) acc[j] += __shfl_xor(acc[j], 32, 64);

    if (half == 0) {
        float4 b0 = ((const float4*)b1)[slot * 2];
        float4 b4 = ((const float4*)b1)[slot * 2 + 1];
        uint4 o;
        o.x = pack2(fmaxf(acc[0] + b0.x, 0.f), fmaxf(acc[1] + b0.y, 0.f));
        o.y = pack2(fmaxf(acc[2] + b0.z, 0.f), fmaxf(acc[3] + b0.w, 0.f));
        o.z = pack2(fmaxf(acc[4] + b4.x, 0.f), fmaxf(acc[5] + b4.y, 0.f));
        o.w = pack2(fmaxf(acc[6] + b4.z, 0.f), fmaxf(acc[7] + b4.w, 0.f));
        ((uint4*)(g + (size_t)wid * F_HID))[slot] = o;
    }
}

// ---------------------------------------------------------------------------
// GEMM2 (MFMA bf16): h2[M,40] = g[M,256] @ W2, K fully LDS-staged.
// h2 rows padded to stride H2_LD=64 ushorts (128 B) for prop2's paired gathers.
// ---------------------------------------------------------------------------

#define G2_LDK 264

__global__ __launch_bounds__(256) void gemm2_mfma(const ushort* __restrict__ G,
                                                  const ushort* __restrict__ BT,
                                                  ushort* __restrict__ H2, int M) {
    __shared__ ushort As[64 * G2_LDK];
    __shared__ ushort Bs[F_OUTP * G2_LDK];
    const int tid  = threadIdx.x;
    const int bm   = blockIdx.x * 64;
    const int wave = tid >> 6;
    const int lane = tid & 63;
    const int quad = lane >> 4;
    const int l16  = lane & 15;

#pragma unroll
    for (int p = 0; p < 8; ++p) {
        int idx = tid + p * 256;
        int r = idx >> 5;
        int c = (idx & 31) * 8;
        uint4 v = make_uint4(0, 0, 0, 0);
        int gr = bm + r;
        if (gr < M) v = *(const uint4*)(G + (size_t)gr * F_HID + c);
        *(uint4*)&As[r * G2_LDK + c] = v;
    }
#pragma unroll
    for (int p = 0; p < 6; ++p) {
        int idx = tid + p * 256;
        int r = idx >> 5;
        int c = (idx & 31) * 8;
        uint4 v = *(const uint4*)(BT + (size_t)r * F_HID + c);
        *(uint4*)&Bs[r * G2_LDK + c] = v;
    }
    __syncthreads();

    f32x4 acc[3] = {};
#pragma unroll
    for (int ks = 0; ks < F_HID / 32; ++ks) {
        bf16x8 a = *(bf16x8*)&As[(wave * 16 + l16) * G2_LDK + ks * 32 + quad * 8];
#pragma unroll
        for (int nt = 0; nt < 3; ++nt) {
            bf16x8 b = *(bf16x8*)&Bs[(nt * 16 + l16) * G2_LDK + ks * 32 + quad * 8];
            acc[nt] = __builtin_amdgcn_mfma_f32_16x16x32_bf16(a, b, acc[nt], 0, 0, 0);
        }
    }

#pragma unroll
    for (int i = 0; i < 4; ++i) {
        int row = bm + wave * 16 + quad * 4 + i;
        if (row < M) {
#pragma unroll
            for (int nt = 0; nt < 3; ++nt) {
                int col = nt * 16 + l16;
                if (col < F_OUT)
                    H2[(size_t)row * H2_LD + col] = f2b(acc[nt][i]);
            }
        }
    }
}

// ---------------------------------------------------------------------------
// Propagate layer 2 (F=40, bf16, 128 B padded rows) + bias + fused
// log_softmax. Same 2-edges-per-gather pairing as prop1. NOTE: after the
// cross-half combine BOTH halves hold full sums — the exp-sum contribution
// must come from half 0 only (round-2 bug: doubled denominator = log(2)
// shift in log_softmax).
// ---------------------------------------------------------------------------

#define P2E 16

__global__ __launch_bounds__(256) void prop2_kernel(const ushort* __restrict__ h2,
                                                    const float* __restrict__ b2,
                                                    const float* __restrict__ dinv,
                                                    const int* __restrict__ rowptr,
                                                    const uint2* __restrict__ edge_s,
                                                    float* __restrict__ out, int N, int E) {
    int wid  = (blockIdx.x * blockDim.x + threadIdx.x) >> 6;
    int lane = threadIdx.x & 63;
    if (wid >= N) return;
    const uint* hq = (const uint*)h2;        // row = 32 uint slots (128 B)
    const int half = lane >> 5;
    const int slot = lane & 31;
    const bool act = slot < (F_OUT / 2);     // features 2*slot, 2*slot+1 valid
    float di = dinv[wid];
    float sn = (half == 0) ? di * di : 0.f;

    float a0, a1;
    {
        uint sv = hq[(size_t)wid * 32 + slot];
        a0 = sn * b2f((ushort)(sv & 0xffffu));
        a1 = sn * b2f((ushort)(sv >> 16));
    }

    int e0 = rowptr[wid], e1 = rowptr[wid + 1];
    const int eE = E - 2;
    for (int e = (e0 & ~1); e < e1; e += P2E) {
        uint4 rec[P2E / 2];
        uint  v[P2E / 2];
        float w[P2E / 2];
#pragma unroll
        for (int u = 0; u < P2E / 2; ++u) {
            int i0 = min(e + 2 * u, eE);
            rec[u] = *(const uint4*)(edge_s + i0);
        }
#pragma unroll
        for (int u = 0; u < P2E / 2; ++u) {
            int idx = e + 2 * u + half;
            uint col = half ? rec[u].z : rec[u].x;
            uint wb  = half ? rec[u].w : rec[u].y;
            w[u] = (idx >= e0 && idx < e1) ? __uint_as_float(wb) : 0.f;
            v[u] = hq[(size_t)col * 32 + slot];
        }
#pragma unroll
        for (int u = 0; u < P2E / 2; ++u) {
            a0 = fmaf(w[u], b2f((ushort)(v[u] & 0xffffu)), a0);
            a1 = fmaf(w[u], b2f((ushort)(v[u] >> 16)), a1);
        }
    }

    a0 += __shfl_xor(a0, 32, 64);
    a1 += __shfl_xor(a1, 32, 64);

    if (act) {                 // exec-masked loads keep b2 (40 floats) in-bounds
        float2 bb = ((const float2*)b2)[slot];
        a0 += bb.x;
        a1 += bb.y;
    }

    float m = act ? fmaxf(a0, a1) : -INFINITY;
#pragma unroll
    for (int o = 32; o; o >>= 1) m = fmaxf(m, __shfl_xor(m, o, 64));
    // exp-sum from half 0 only: both halves hold full sums post-combine
    float ex = (act && half == 0) ? (expf(a0 - m) + expf(a1 - m)) : 0.f;
    float s = ex;
#pragma unroll
    for (int o = 32; o; o >>= 1) s += __shfl_xor(s, o, 64);

    if (half == 0 && act) {
        float ls = m + logf(s);
        size_t base = (size_t)wid * F_OUT + 2 * slot;
        float2 o1; o1.x = a0; o1.y = a1;
        float2 o2; o2.x = a0 - ls; o2.y = a1 - ls;
        *(float2*)(out + base) = o1;
        *(float2*)(out + (size_t)N * F_OUT + base) = o2;
    }
}

// ---------------------------------------------------------------------------
// Launch
// ---------------------------------------------------------------------------

extern "C" void kernel_launch(void* const* d_in, const int* in_sizes, int n_in,
                              void* d_out, int out_size, void* d_ws, size_t ws_size,
                              hipStream_t stream) {
    const float* x  = (const float*)d_in[0];
    const int*   ei = (const int*)d_in[1];
    const float* W1 = (const float*)d_in[2];
    const float* b1 = (const float*)d_in[3];
    const float* W2 = (const float*)d_in[4];
    const float* b2 = (const float*)d_in[5];
    float* out = (float*)d_out;

    const int N = in_sizes[0] / F_IN;
    const int E = in_sizes[1] / 2;
    const int NR = (N + HBINS - 1) / HBINS;

    char* p = (char*)d_ws;
    auto alloc = [&](size_t bytes) -> char* {
        char* q = p;
        p += (bytes + 255) & ~(size_t)255;
        return q;
    };
    int*    cnt_row = (int*)alloc((size_t)N * 4);
    int*    rowptr  = (int*)alloc((size_t)(N + 1) * 4);
    float*  dinv    = (float*)alloc((size_t)N * 4);
    uint2*  edge_s  = (uint2*)alloc((size_t)E * 8);
    int*    part    = (int*)alloc((size_t)2 * NR * HSLICES * HBINS * 4);
    int*    offs    = (int*)alloc((size_t)NR * HSLICES * HBINS * 4);
    ushort* W1T     = (ushort*)alloc((size_t)F_HID * F_IN * 2);
    ushort* W2T     = (ushort*)alloc((size_t)F_OUTP * F_HID * 2);
    unsigned char* h = (unsigned char*)alloc((size_t)N * F_HID);   // fp8 e4m3
    ushort* g       = (ushort*)alloc((size_t)N * F_HID * 2);
    ushort* h2      = (ushort*)alloc((size_t)N * H2_LD * 2);       // padded rows

    dim3 hgrid(HSLICES, NR, 2);
    hist_kernel<<<hgrid, 1024, 0, stream>>>(ei, part, E, NR);
    hist_reduce<<<(2 * N + 255) / 256, 256, 0, stream>>>(part, cnt_row, dinv, N, NR);
    scan_kernel<<<1, 1024, 0, stream>>>(cnt_row, rowptr, N);
    slice_scan<<<(NR * HBINS + 255) / 256, 256, 0, stream>>>(part, rowptr, offs, N, NR);

    dim3 pgrid(HSLICES, NR);
    place_kernel<<<pgrid, 1024, 0, stream>>>(ei, dinv, offs, edge_s, E, NR);

    int prep_total = F_HID * F_IN + F_OUTP * F_HID;
    prep_weights<<<(prep_total + 255) / 256, 256, 0, stream>>>(W1, W2, W1T, W2T);

    gemm1_mfma<<<(N + 63) / 64, 256, 0, stream>>>(x, W1T, h, N);
    prop1_kernel<<<(N + 3) / 4, 256, 0, stream>>>(h, b1, dinv, rowptr, edge_s, g, N, E);
    gemm2_mfma<<<(N + 63) / 64, 256, 0, stream>>>(g, W2T, h2, N);
    prop2_kernel<<<(N + 3) / 4, 256, 0, stream>>>(h2, b2, dinv, rowptr, edge_s, out, N, E);
}

// Round 4
// 863.933 us; speedup vs baseline: 1.7344x; 1.7344x over previous
//
#include <hip/hip_runtime.h>
#include <cstdint>
#include <cstddef>

#define F_IN  512
#define F_HID 256
#define F_OUT 40
#define F_OUTP 48    // padded to 3x16 MFMA tiles
#define H2_LD 64     // h2 row stride in ushorts (128 B, 2 lines, aligned)

#define HBINS 16384        // 64 KB LDS histogram bins
#define HSLICES 36         // edge slices for hist/place passes

typedef short  bf16x8 __attribute__((ext_vector_type(8)));
typedef float  f32x4  __attribute__((ext_vector_type(4)));
typedef float  f32x2  __attribute__((ext_vector_type(2)));

__device__ __forceinline__ ushort f2b(float f) {   // fp32 -> bf16 RNE
    uint u = __float_as_uint(f);
    return (ushort)((u + 0x7FFFu + ((u >> 16) & 1u)) >> 16);
}
__device__ __forceinline__ uint pack2(float a, float b) {
    return (uint)f2b(a) | ((uint)f2b(b) << 16);
}
__device__ __forceinline__ float b2f(ushort u) {
    return __uint_as_float(((uint)u) << 16);
}

// ---------------------------------------------------------------------------
// Degree histogram WITHOUT global atomics: block (slice s, range r, array a)
// scans its edge slice, counts indices in [r*HBINS, r*HBINS+HBINS) into an LDS
// histogram, writes the 64 KB partial to scratch non-atomically.
// ---------------------------------------------------------------------------

__global__ __launch_bounds__(1024) void hist_kernel(const int* __restrict__ ei,
                                                    int* __restrict__ part,
                                                    int E, int NR) {
    __shared__ int hist[HBINS];
    const int tid = threadIdx.x;
    const int s = blockIdx.x;
    const int r = blockIdx.y;
    const int a = blockIdx.z;
    const int* src = ei + (size_t)a * E;   // a=0: row, a=1: col
    const uint base = (uint)r * HBINS;

    for (int i = tid; i < HBINS; i += 1024) hist[i] = 0;
    __syncthreads();

    int elen  = (E + HSLICES - 1) / HSLICES;
    int start = s * elen;
    int end   = min(start + elen, E);
    for (int i = start + tid; i < end; i += 1024) {
        uint b = (uint)src[i] - base;
        if (b < HBINS) atomicAdd(&hist[b], 1);
    }
    __syncthreads();

    int* dst = part + ((size_t)(a * NR + r) * HSLICES + s) * HBINS;
    for (int i = tid; i < HBINS; i += 1024) dst[i] = hist[i];
}

// Sum the HSLICES partials per (array, node). a=0 -> cnt_row; a=1 -> dinv.
__global__ void hist_reduce(const int* __restrict__ part,
                            int* __restrict__ cnt_row,
                            float* __restrict__ dinv, int N, int NR) {
    int t = blockIdx.x * blockDim.x + threadIdx.x;
    if (t >= 2 * N) return;
    int a = (t >= N) ? 1 : 0;
    int i = t - a * N;
    int r = i >> 14;             // / HBINS
    int bin = i & (HBINS - 1);
    const int* p = part + ((size_t)(a * NR + r) * HSLICES) * HBINS + bin;
    int sum = 0;
#pragma unroll 4
    for (int s = 0; s < HSLICES; ++s) sum += p[(size_t)s * HBINS];
    if (a == 0) cnt_row[i] = sum;
    else        dinv[i] = rsqrtf((float)(sum + 1));
}

// ---------------------------------------------------------------------------
// Single-block exclusive scan of cnt_row -> rowptr[N+1].
// ---------------------------------------------------------------------------

__global__ __launch_bounds__(1024) void scan_kernel(const int* __restrict__ cnt,
                                                    int* __restrict__ rowptr, int N) {
    __shared__ int sums[1024];
    int tid = threadIdx.x;
    int chunk = (N + 1023) >> 10;
    int s0 = tid * chunk;
    int s1 = s0 + chunk;
    if (s0 > N) s0 = N;
    if (s1 > N) s1 = N;
    int sum = 0;
    for (int i = s0; i < s1; ++i) sum += cnt[i];
    sums[tid] = sum;
    __syncthreads();
    for (int off = 1; off < 1024; off <<= 1) {
        int v = (tid >= off) ? sums[tid - off] : 0;
        __syncthreads();
        sums[tid] += v;
        __syncthreads();
    }
    int base = (tid > 0) ? sums[tid - 1] : 0;
    for (int i = s0; i < s1; ++i) {
        rowptr[i] = base;
        base += cnt[i];
    }
    if (tid == 0) rowptr[N] = sums[1023];
}

// ---------------------------------------------------------------------------
// offs[r][s][bin] = rowptr[node] + sum_{s'<s} part[a=0][r][s'][bin].
// One thread per node; per-s writes are lane-consecutive -> coalesced.
// ---------------------------------------------------------------------------

__global__ void slice_scan(const int* __restrict__ part,
                           const int* __restrict__ rowptr,
                           int* __restrict__ offs, int N, int NR) {
    int i = blockIdx.x * blockDim.x + threadIdx.x;
    if (i >= NR * HBINS) return;
    int r = i >> 14;
    int bin = i & (HBINS - 1);
    int acc = (i < N) ? rowptr[i] : 0;
    const int* p = part + ((size_t)r * HSLICES) * HBINS + bin;   // a=0 block
    int* o = offs + ((size_t)r * HSLICES) * HBINS + bin;
    for (int s = 0; s < HSLICES; ++s) {
        o[(size_t)s * HBINS] = acc;
        acc += p[(size_t)s * HBINS];
    }
}

// ---------------------------------------------------------------------------
// CSR placement with LDS cursors only (no global atomics). Block (s, r) loads
// its offset slab into LDS, re-scans its edge slice, places in-range edges.
// ---------------------------------------------------------------------------

__global__ __launch_bounds__(1024) void place_kernel(const int* __restrict__ ei,
                                                     const float* __restrict__ dinv,
                                                     const int* __restrict__ offs,
                                                     uint2* __restrict__ edge_s,
                                                     int E, int NR) {
    __shared__ int cur[HBINS];
    const int tid = threadIdx.x;
    const int s = blockIdx.x;
    const int r = blockIdx.y;
    const int* row = ei;
    const int* col = ei + E;
    const uint base = (uint)r * HBINS;
    const int* oslab = offs + ((size_t)r * HSLICES + s) * HBINS;

    for (int i = tid; i < HBINS; i += 1024) cur[i] = oslab[i];
    __syncthreads();

    int elen  = (E + HSLICES - 1) / HSLICES;
    int start = s * elen;
    int end   = min(start + elen, E);
    for (int i = start + tid; i < end; i += 1024) {
        uint b = (uint)row[i] - base;
        if (b < HBINS) {
            int pos = atomicAdd(&cur[b], 1);
            int c = col[i];
            uint2 v;
            v.x = (uint)c;
            v.y = __float_as_uint(dinv[base + b] * dinv[c]);
            edge_s[pos] = v;
        }
    }
}

// ---------------------------------------------------------------------------
// Weight prep: W1T [256][512] bf16 (= W1^T), W2T [48][256] bf16 (rows 40..47=0).
// ---------------------------------------------------------------------------

__global__ void prep_weights(const float* __restrict__ W1, const float* __restrict__ W2,
                             ushort* __restrict__ W1T, ushort* __restrict__ W2T) {
    int t = blockIdx.x * blockDim.x + threadIdx.x;
    if (t < F_HID * F_IN) {
        int n = t >> 9, k = t & 511;
        W1T[t] = f2b(W1[(size_t)k * F_HID + n]);
        return;
    }
    int u = t - F_HID * F_IN;
    if (u < F_OUTP * F_HID) {
        int n = u >> 8, k = u & 255;
        W2T[u] = f2b((n < F_OUT) ? W2[(size_t)k * F_OUT + n] : 0.f);
    }
}

// ---------------------------------------------------------------------------
// GEMM1 (MFMA bf16): h[M,256] = x[M,512] @ W1.  BM=64, BN=256, BK=32.
// Output h stored as fp8 e4m3 (256 B/row) for prop1's gathers.
// ---------------------------------------------------------------------------

#define G1_LDK 40

__global__ __launch_bounds__(256) void gemm1_mfma(const float* __restrict__ A,
                                                  const ushort* __restrict__ BT,
                                                  unsigned char* __restrict__ C, int M) {
    __shared__ ushort As[64 * G1_LDK];
    __shared__ ushort Bs[256 * G1_LDK];
    const int tid  = threadIdx.x;
    const int bm   = blockIdx.x * 64;
    const int wave = tid >> 6;
    const int lane = tid & 63;
    const int quad = lane >> 4;
    const int l16  = lane & 15;

    f32x4 acc[4][4] = {};

    const int ar = tid >> 2;
    const int ac = (tid & 3) * 8;

    for (int k0 = 0; k0 < F_IN; k0 += 32) {
        {
            int gr = bm + ar;
            float4 v0 = make_float4(0.f, 0.f, 0.f, 0.f), v1 = v0;
            if (gr < M) {
                const float* ap = A + (size_t)gr * F_IN + k0 + ac;
                v0 = *(const float4*)(ap);
                v1 = *(const float4*)(ap + 4);
            }
            uint4 w;
            w.x = pack2(v0.x, v0.y);
            w.y = pack2(v0.z, v0.w);
            w.z = pack2(v1.x, v1.y);
            w.w = pack2(v1.z, v1.w);
            *(uint4*)&As[ar * G1_LDK + ac] = w;
        }
#pragma unroll
        for (int p = 0; p < 4; ++p) {
            int idx = tid + p * 256;
            int r = idx >> 2;
            int c = (idx & 3) * 8;
            uint4 v = *(const uint4*)(BT + (size_t)r * F_IN + k0 + c);
            *(uint4*)&Bs[r * G1_LDK + c] = v;
        }
        __syncthreads();

        bf16x8 af[4], bfr[4];
#pragma unroll
        for (int mt = 0; mt < 4; ++mt)
            af[mt] = *(bf16x8*)&As[(mt * 16 + l16) * G1_LDK + quad * 8];
#pragma unroll
        for (int nt = 0; nt < 4; ++nt)
            bfr[nt] = *(bf16x8*)&Bs[(wave * 64 + nt * 16 + l16) * G1_LDK + quad * 8];
#pragma unroll
        for (int mt = 0; mt < 4; ++mt)
#pragma unroll
            for (int nt = 0; nt < 4; ++nt)
                acc[mt][nt] = __builtin_amdgcn_mfma_f32_16x16x32_bf16(af[mt], bfr[nt],
                                                                     acc[mt][nt], 0, 0, 0);
        __syncthreads();
    }

#pragma unroll
    for (int mt = 0; mt < 4; ++mt) {
#pragma unroll
        for (int i = 0; i < 4; ++i) {
            int row = bm + mt * 16 + quad * 4 + i;
            if (row < M) {
#pragma unroll
                for (int nt = 0; nt < 4; ++nt) {
                    int col = wave * 64 + nt * 16 + l16;
                    uint pk = (uint)__builtin_amdgcn_cvt_pk_fp8_f32(acc[mt][nt][i], 0.f, 0, false);
                    C[(size_t)row * F_HID + col] = (unsigned char)pk;
                }
            }
        }
    }
}

// ---------------------------------------------------------------------------
// Propagate layer 1 (F=256, fp8) + bias + ReLU. TWO edges per wave gather
// instruction: lanes 0-31 load edge A's row (8 B/lane dwordx2), lanes 32-63
// edge B's. Edge records loaded PER-LANE as uint2 (half 0 -> record 2u,
// half 1 -> record 2u+1; same cache line) — 16 VGPR live instead of the
// uint4 rec buffer (32 VGPR) that spilled 2 GB to scratch in round 3.
// __launch_bounds__(256,4) caps at 4 waves/EU -> 128 VGPR budget, no spill.
// ---------------------------------------------------------------------------

#define P1E 16   // edges per iteration = 8 aligned pairs

__global__ __launch_bounds__(256, 4) void prop1_kernel(const unsigned char* __restrict__ h,
                                                       const float* __restrict__ b1,
                                                       const float* __restrict__ dinv,
                                                       const int* __restrict__ rowptr,
                                                       const uint2* __restrict__ edge_s,
                                                       ushort* __restrict__ g, int N, int E) {
    int wid  = (blockIdx.x * blockDim.x + threadIdx.x) >> 6;
    int lane = threadIdx.x & 63;
    if (wid >= N) return;
    const uint2* hq = (const uint2*)h;      // row = 32 uint2 slots (256 B)
    const int half = lane >> 5;
    const int slot = lane & 31;
    float di = dinv[wid];
    float sn = (half == 0) ? di * di : 0.f;   // self term counted once (low half)

    float acc[8];
    {
        uint2 sv = hq[(size_t)wid * 32 + slot];
        f32x2 a01 = __builtin_amdgcn_cvt_pk_f32_fp8((int)sv.x, false);
        f32x2 a23 = __builtin_amdgcn_cvt_pk_f32_fp8((int)sv.x, true);
        f32x2 a45 = __builtin_amdgcn_cvt_pk_f32_fp8((int)sv.y, false);
        f32x2 a67 = __builtin_amdgcn_cvt_pk_f32_fp8((int)sv.y, true);
        acc[0] = sn * a01.x; acc[1] = sn * a01.y;
        acc[2] = sn * a23.x; acc[3] = sn * a23.y;
        acc[4] = sn * a45.x; acc[5] = sn * a45.y;
        acc[6] = sn * a67.x; acc[7] = sn * a67.y;
    }

    int e0 = rowptr[wid], e1 = rowptr[wid + 1];
    const int eE = E - 2;                    // last aligned pair start
    for (int e = (e0 & ~1); e < e1; e += P1E) {
        uint2 rc[P1E / 2];                   // per-lane (col, weight) of MY edge
        uint2 v[P1E / 2];
        float w[P1E / 2];
#pragma unroll
        for (int u = 0; u < P1E / 2; ++u) {
            int i0 = min(e + 2 * u, eE);     // even pair base, clamped in-bounds
            rc[u] = edge_s[i0 + half];
        }
#pragma unroll
        for (int u = 0; u < P1E / 2; ++u) {
            int idx = e + 2 * u + half;
            w[u] = (idx >= e0 && idx < e1) ? __uint_as_float(rc[u].y) : 0.f;
            v[u] = hq[(size_t)rc[u].x * 32 + slot];
        }
#pragma unroll
        for (int u = 0; u < P1E / 2; ++u) {
            f32x2 a01 = __builtin_amdgcn_cvt_pk_f32_fp8((int)v[u].x, false);
            f32x2 a23 = __builtin_amdgcn_cvt_pk_f32_fp8((int)v[u].x, true);
            f32x2 a45 = __builtin_amdgcn_cvt_pk_f32_fp8((int)v[u].y, false);
            f32x2 a67 = __builtin_amdgcn_cvt_pk_f32_fp8((int)v[u].y, true);
            acc[0] = fmaf(w[u], a01.x, acc[0]); acc[1] = fmaf(w[u], a01.y, acc[1]);
            acc[2] = fmaf(w[u], a23.x, acc[2]); acc[3] = fmaf(w[u], a23.y, acc[3]);
            acc[4] = fmaf(w[u], a45.x, acc[4]); acc[5] = fmaf(w[u], a45.y, acc[5]);
            acc[6] = fmaf(w[u], a67.x, acc[6]); acc[7] = fmaf(w[u], a67.y, acc[7]);
        }
    }

#pragma unroll
    for (int j = 0; j < 8; ++j) acc[j] += __shfl_xor(acc[j], 32, 64);

    if (half == 0) {
        float4 b0 = ((const float4*)b1)[slot * 2];
        float4 b4 = ((const float4*)b1)[slot * 2 + 1];
        uint4 o;
        o.x = pack2(fmaxf(acc[0] + b0.x, 0.f), fmaxf(acc[1] + b0.y, 0.f));
        o.y = pack2(fmaxf(acc[2] + b0.z, 0.f), fmaxf(acc[3] + b0.w, 0.f));
        o.z = pack2(fmaxf(acc[4] + b4.x, 0.f), fmaxf(acc[5] + b4.y, 0.f));
        o.w = pack2(fmaxf(acc[6] + b4.z, 0.f), fmaxf(acc[7] + b4.w, 0.f));
        ((uint4*)(g + (size_t)wid * F_HID))[slot] = o;
    }
}

// ---------------------------------------------------------------------------
// GEMM2 (MFMA bf16): h2[M,40] = g[M,256] @ W2, K fully LDS-staged.
// h2 rows padded to stride H2_LD=64 ushorts (128 B) for prop2's paired gathers.
// ---------------------------------------------------------------------------

#define G2_LDK 264

__global__ __launch_bounds__(256) void gemm2_mfma(const ushort* __restrict__ G,
                                                  const ushort* __restrict__ BT,
                                                  ushort* __restrict__ H2, int M) {
    __shared__ ushort As[64 * G2_LDK];
    __shared__ ushort Bs[F_OUTP * G2_LDK];
    const int tid  = threadIdx.x;
    const int bm   = blockIdx.x * 64;
    const int wave = tid >> 6;
    const int lane = tid & 63;
    const int quad = lane >> 4;
    const int l16  = lane & 15;

#pragma unroll
    for (int p = 0; p < 8; ++p) {
        int idx = tid + p * 256;
        int r = idx >> 5;
        int c = (idx & 31) * 8;
        uint4 v = make_uint4(0, 0, 0, 0);
        int gr = bm + r;
        if (gr < M) v = *(const uint4*)(G + (size_t)gr * F_HID + c);
        *(uint4*)&As[r * G2_LDK + c] = v;
    }
#pragma unroll
    for (int p = 0; p < 6; ++p) {
        int idx = tid + p * 256;
        int r = idx >> 5;
        int c = (idx & 31) * 8;
        uint4 v = *(const uint4*)(BT + (size_t)r * F_HID + c);
        *(uint4*)&Bs[r * G2_LDK + c] = v;
    }
    __syncthreads();

    f32x4 acc[3] = {};
#pragma unroll
    for (int ks = 0; ks < F_HID / 32; ++ks) {
        bf16x8 a = *(bf16x8*)&As[(wave * 16 + l16) * G2_LDK + ks * 32 + quad * 8];
#pragma unroll
        for (int nt = 0; nt < 3; ++nt) {
            bf16x8 b = *(bf16x8*)&Bs[(nt * 16 + l16) * G2_LDK + ks * 32 + quad * 8];
            acc[nt] = __builtin_amdgcn_mfma_f32_16x16x32_bf16(a, b, acc[nt], 0, 0, 0);
        }
    }

#pragma unroll
    for (int i = 0; i < 4; ++i) {
        int row = bm + wave * 16 + quad * 4 + i;
        if (row < M) {
#pragma unroll
            for (int nt = 0; nt < 3; ++nt) {
                int col = nt * 16 + l16;
                if (col < F_OUT)
                    H2[(size_t)row * H2_LD + col] = f2b(acc[nt][i]);
            }
        }
    }
}

// ---------------------------------------------------------------------------
// Propagate layer 2 (F=40, bf16, 128 B padded rows) + bias + fused
// log_softmax. Same 2-edges-per-gather pairing + per-lane uint2 records as
// prop1. exp-sum from half 0 only (both halves hold full sums post-combine).
// ---------------------------------------------------------------------------

#define P2E 16

__global__ __launch_bounds__(256, 4) void prop2_kernel(const ushort* __restrict__ h2,
                                                       const float* __restrict__ b2,
                                                       const float* __restrict__ dinv,
                                                       const int* __restrict__ rowptr,
                                                       const uint2* __restrict__ edge_s,
                                                       float* __restrict__ out, int N, int E) {
    int wid  = (blockIdx.x * blockDim.x + threadIdx.x) >> 6;
    int lane = threadIdx.x & 63;
    if (wid >= N) return;
    const uint* hq = (const uint*)h2;        // row = 32 uint slots (128 B)
    const int half = lane >> 5;
    const int slot = lane & 31;
    const bool act = slot < (F_OUT / 2);     // features 2*slot, 2*slot+1 valid
    float di = dinv[wid];
    float sn = (half == 0) ? di * di : 0.f;

    float a0, a1;
    {
        uint sv = hq[(size_t)wid * 32 + slot];
        a0 = sn * b2f((ushort)(sv & 0xffffu));
        a1 = sn * b2f((ushort)(sv >> 16));
    }

    int e0 = rowptr[wid], e1 = rowptr[wid + 1];
    const int eE = E - 2;
    for (int e = (e0 & ~1); e < e1; e += P2E) {
        uint2 rc[P2E / 2];
        uint  v[P2E / 2];
        float w[P2E / 2];
#pragma unroll
        for (int u = 0; u < P2E / 2; ++u) {
            int i0 = min(e + 2 * u, eE);
            rc[u] = edge_s[i0 + half];
        }
#pragma unroll
        for (int u = 0; u < P2E / 2; ++u) {
            int idx = e + 2 * u + half;
            w[u] = (idx >= e0 && idx < e1) ? __uint_as_float(rc[u].y) : 0.f;
            v[u] = hq[(size_t)rc[u].x * 32 + slot];
        }
#pragma unroll
        for (int u = 0; u < P2E / 2; ++u) {
            a0 = fmaf(w[u], b2f((ushort)(v[u] & 0xffffu)), a0);
            a1 = fmaf(w[u], b2f((ushort)(v[u] >> 16)), a1);
        }
    }

    a0 += __shfl_xor(a0, 32, 64);
    a1 += __shfl_xor(a1, 32, 64);

    if (act) {                 // exec-masked loads keep b2 (40 floats) in-bounds
        float2 bb = ((const float2*)b2)[slot];
        a0 += bb.x;
        a1 += bb.y;
    }

    float m = act ? fmaxf(a0, a1) : -INFINITY;
#pragma unroll
    for (int o = 32; o; o >>= 1) m = fmaxf(m, __shfl_xor(m, o, 64));
    // exp-sum from half 0 only: both halves hold full sums post-combine
    float ex = (act && half == 0) ? (expf(a0 - m) + expf(a1 - m)) : 0.f;
    float s = ex;
#pragma unroll
    for (int o = 32; o; o >>= 1) s += __shfl_xor(s, o, 64);

    if (half == 0 && act) {
        float ls = m + logf(s);
        size_t base = (size_t)wid * F_OUT + 2 * slot;
        float2 o1; o1.x = a0; o1.y = a1;
        float2 o2; o2.x = a0 - ls; o2.y = a1 - ls;
        *(float2*)(out + base) = o1;
        *(float2*)(out + (size_t)N * F_OUT + base) = o2;
    }
}

// ---------------------------------------------------------------------------
// Launch
// ---------------------------------------------------------------------------

extern "C" void kernel_launch(void* const* d_in, const int* in_sizes, int n_in,
                              void* d_out, int out_size, void* d_ws, size_t ws_size,
                              hipStream_t stream) {
    const float* x  = (const float*)d_in[0];
    const int*   ei = (const int*)d_in[1];
    const float* W1 = (const float*)d_in[2];
    const float* b1 = (const float*)d_in[3];
    const float* W2 = (const float*)d_in[4];
    const float* b2 = (const float*)d_in[5];
    float* out = (float*)d_out;

    const int N = in_sizes[0] / F_IN;
    const int E = in_sizes[1] / 2;
    const int NR = (N + HBINS - 1) / HBINS;

    char* p = (char*)d_ws;
    auto alloc = [&](size_t bytes) -> char* {
        char* q = p;
        p += (bytes + 255) & ~(size_t)255;
        return q;
    };
    int*    cnt_row = (int*)alloc((size_t)N * 4);
    int*    rowptr  = (int*)alloc((size_t)(N + 1) * 4);
    float*  dinv    = (float*)alloc((size_t)N * 4);
    uint2*  edge_s  = (uint2*)alloc((size_t)E * 8);
    int*    part    = (int*)alloc((size_t)2 * NR * HSLICES * HBINS * 4);
    int*    offs    = (int*)alloc((size_t)NR * HSLICES * HBINS * 4);
    ushort* W1T     = (ushort*)alloc((size_t)F_HID * F_IN * 2);
    ushort* W2T     = (ushort*)alloc((size_t)F_OUTP * F_HID * 2);
    unsigned char* h = (unsigned char*)alloc((size_t)N * F_HID);   // fp8 e4m3
    ushort* g       = (ushort*)alloc((size_t)N * F_HID * 2);
    ushort* h2      = (ushort*)alloc((size_t)N * H2_LD * 2);       // padded rows

    dim3 hgrid(HSLICES, NR, 2);
    hist_kernel<<<hgrid, 1024, 0, stream>>>(ei, part, E, NR);
    hist_reduce<<<(2 * N + 255) / 256, 256, 0, stream>>>(part, cnt_row, dinv, N, NR);
    scan_kernel<<<1, 1024, 0, stream>>>(cnt_row, rowptr, N);
    slice_scan<<<(NR * HBINS + 255) / 256, 256, 0, stream>>>(part, rowptr, offs, N, NR);

    dim3 pgrid(HSLICES, NR);
    place_kernel<<<pgrid, 1024, 0, stream>>>(ei, dinv, offs, edge_s, E, NR);

    int prep_total = F_HID * F_IN + F_OUTP * F_HID;
    prep_weights<<<(prep_total + 255) / 256, 256, 0, stream>>>(W1, W2, W1T, W2T);

    gemm1_mfma<<<(N + 63) / 64, 256, 0, stream>>>(x, W1T, h, N);
    prop1_kernel<<<(N + 3) / 4, 256, 0, stream>>>(h, b1, dinv, rowptr, edge_s, g, N, E);
    gemm2_mfma<<<(N + 63) / 64, 256, 0, stream>>>(g, W2T, h2, N);
    prop2_kernel<<<(N + 3) / 4, 256, 0, stream>>>(h2, b2, dinv, rowptr, edge_s, out, N, E);
}

// Round 5
// 715.786 us; speedup vs baseline: 2.0934x; 1.2070x over previous
//
#include <hip/hip_runtime.h>
#include <cstdint>
#include <cstddef>

#define F_IN  512
#define F_HID 256
#define F_OUT 40
#define F_OUTP 48    // padded to 3x16 MFMA tiles
#define H2_LD 64     // h2 row stride in ushorts (128 B, 2 lines, aligned)

#define HBINS 16384        // 64 KB LDS histogram bins
#define HSLICES 36         // edge slices for hist/place passes

typedef short  bf16x8 __attribute__((ext_vector_type(8)));
typedef float  f32x4  __attribute__((ext_vector_type(4)));
typedef float  f32x2  __attribute__((ext_vector_type(2)));

__device__ __forceinline__ ushort f2b(float f) {   // fp32 -> bf16 RNE
    uint u = __float_as_uint(f);
    return (ushort)((u + 0x7FFFu + ((u >> 16) & 1u)) >> 16);
}
__device__ __forceinline__ uint pack2(float a, float b) {
    return (uint)f2b(a) | ((uint)f2b(b) << 16);
}
__device__ __forceinline__ float b2f(ushort u) {
    return __uint_as_float(((uint)u) << 16);
}

// ---------------------------------------------------------------------------
// Degree histogram WITHOUT global atomics: block (slice s, range r, array a)
// scans its edge slice, counts indices in [r*HBINS, r*HBINS+HBINS) into an LDS
// histogram, writes the 64 KB partial to scratch non-atomically.
// ---------------------------------------------------------------------------

__global__ __launch_bounds__(1024) void hist_kernel(const int* __restrict__ ei,
                                                    int* __restrict__ part,
                                                    int E, int NR) {
    __shared__ int hist[HBINS];
    const int tid = threadIdx.x;
    const int s = blockIdx.x;
    const int r = blockIdx.y;
    const int a = blockIdx.z;
    const int* src = ei + (size_t)a * E;   // a=0: row, a=1: col
    const uint base = (uint)r * HBINS;

    for (int i = tid; i < HBINS; i += 1024) hist[i] = 0;
    __syncthreads();

    int elen  = (E + HSLICES - 1) / HSLICES;
    int start = s * elen;
    int end   = min(start + elen, E);
    for (int i = start + tid; i < end; i += 1024) {
        uint b = (uint)src[i] - base;
        if (b < HBINS) atomicAdd(&hist[b], 1);
    }
    __syncthreads();

    int* dst = part + ((size_t)(a * NR + r) * HSLICES + s) * HBINS;
    for (int i = tid; i < HBINS; i += 1024) dst[i] = hist[i];
}

// Sum the HSLICES partials per (array, node). a=0 -> cnt_row; a=1 -> dinv.
__global__ void hist_reduce(const int* __restrict__ part,
                            int* __restrict__ cnt_row,
                            float* __restrict__ dinv, int N, int NR) {
    int t = blockIdx.x * blockDim.x + threadIdx.x;
    if (t >= 2 * N) return;
    int a = (t >= N) ? 1 : 0;
    int i = t - a * N;
    int r = i >> 14;             // / HBINS
    int bin = i & (HBINS - 1);
    const int* p = part + ((size_t)(a * NR + r) * HSLICES) * HBINS + bin;
    int sum = 0;
#pragma unroll 4
    for (int s = 0; s < HSLICES; ++s) sum += p[(size_t)s * HBINS];
    if (a == 0) cnt_row[i] = sum;
    else        dinv[i] = rsqrtf((float)(sum + 1));
}

// ---------------------------------------------------------------------------
// Multi-block exclusive scan of cnt_row -> rowptr[N+1]. Replaces the serial
// single-block scan (161 us, 0.16% occupancy): 3 phases, each fully parallel.
// ---------------------------------------------------------------------------

// Phase 1: block b writes sum of cnt[b*1024 .. b*1024+1023] to bsum[b].
__global__ __launch_bounds__(1024) void scan_part(const int* __restrict__ cnt,
                                                  int* __restrict__ bsum, int N) {
    __shared__ int wred[16];
    int tid = threadIdx.x;
    int i = blockIdx.x * 1024 + tid;
    int v = (i < N) ? cnt[i] : 0;
#pragma unroll
    for (int o = 32; o; o >>= 1) v += __shfl_xor(v, o, 64);
    int wid = tid >> 6, lane = tid & 63;
    if (lane == 0) wred[wid] = v;
    __syncthreads();
    if (tid < 16) {
        int s = wred[tid];
#pragma unroll
        for (int o = 8; o; o >>= 1) s += __shfl_xor(s, o, 64);
        if (tid == 0) bsum[blockIdx.x] = s;
    }
}

// Phase 2: single block exclusive-scans bsum[0..NB) in LDS (NB <= 1024),
// writes rowptr[N] = grand total.
__global__ __launch_bounds__(1024) void scan_bsum(int* __restrict__ bsum,
                                                  int* __restrict__ rowptr,
                                                  int NB, int N) {
    __shared__ int s[1024];
    int tid = threadIdx.x;
    s[tid] = (tid < NB) ? bsum[tid] : 0;
    __syncthreads();
    for (int off = 1; off < 1024; off <<= 1) {
        int v = (tid >= off) ? s[tid - off] : 0;
        __syncthreads();
        s[tid] += v;
        __syncthreads();
    }
    if (tid < NB) bsum[tid] = (tid > 0) ? s[tid - 1] : 0;
    if (tid == 0) rowptr[N] = s[1023];
}

// Phase 3: block b re-reads its chunk, block-wide exclusive scan + bsum[b].
__global__ __launch_bounds__(1024) void scan_write(const int* __restrict__ cnt,
                                                   const int* __restrict__ bsum,
                                                   int* __restrict__ rowptr, int N) {
    __shared__ int wsum[16];
    int tid = threadIdx.x;
    int wid = tid >> 6, lane = tid & 63;
    int i = blockIdx.x * 1024 + tid;
    int v = (i < N) ? cnt[i] : 0;
    int incl = v;
#pragma unroll
    for (int o = 1; o < 64; o <<= 1) {
        int t = __shfl_up(incl, o, 64);
        if (lane >= o) incl += t;
    }
    if (lane == 63) wsum[wid] = incl;
    __syncthreads();
    if (tid < 16) {
        int s = wsum[tid];
#pragma unroll
        for (int o = 1; o < 16; o <<= 1) {
            int t = __shfl_up(s, o, 64);
            if (tid >= o) s += t;
        }
        wsum[tid] = s;   // inclusive scan of wave sums
    }
    __syncthreads();
    int base = bsum[blockIdx.x] + ((wid > 0) ? wsum[wid - 1] : 0);
    if (i < N) rowptr[i] = base + incl - v;   // exclusive
}

// ---------------------------------------------------------------------------
// offs[r][s][bin] = rowptr[node] + sum_{s'<s} part[a=0][r][s'][bin].
// One thread per node; per-s writes are lane-consecutive -> coalesced.
// ---------------------------------------------------------------------------

__global__ void slice_scan(const int* __restrict__ part,
                           const int* __restrict__ rowptr,
                           int* __restrict__ offs, int N, int NR) {
    int i = blockIdx.x * blockDim.x + threadIdx.x;
    if (i >= NR * HBINS) return;
    int r = i >> 14;
    int bin = i & (HBINS - 1);
    int acc = (i < N) ? rowptr[i] : 0;
    const int* p = part + ((size_t)r * HSLICES) * HBINS + bin;   // a=0 block
    int* o = offs + ((size_t)r * HSLICES) * HBINS + bin;
    for (int s = 0; s < HSLICES; ++s) {
        o[(size_t)s * HBINS] = acc;
        acc += p[(size_t)s * HBINS];
    }
}

// ---------------------------------------------------------------------------
// CSR placement with LDS cursors only (no global atomics). Block (s, r) loads
// its offset slab into LDS, re-scans its edge slice, places in-range edges.
// ---------------------------------------------------------------------------

__global__ __launch_bounds__(1024) void place_kernel(const int* __restrict__ ei,
                                                     const float* __restrict__ dinv,
                                                     const int* __restrict__ offs,
                                                     uint2* __restrict__ edge_s,
                                                     int E, int NR) {
    __shared__ int cur[HBINS];
    const int tid = threadIdx.x;
    const int s = blockIdx.x;
    const int r = blockIdx.y;
    const int* row = ei;
    const int* col = ei + E;
    const uint base = (uint)r * HBINS;
    const int* oslab = offs + ((size_t)r * HSLICES + s) * HBINS;

    for (int i = tid; i < HBINS; i += 1024) cur[i] = oslab[i];
    __syncthreads();

    int elen  = (E + HSLICES - 1) / HSLICES;
    int start = s * elen;
    int end   = min(start + elen, E);
    for (int i = start + tid; i < end; i += 1024) {
        uint b = (uint)row[i] - base;
        if (b < HBINS) {
            int pos = atomicAdd(&cur[b], 1);
            int c = col[i];
            uint2 v;
            v.x = (uint)c;
            v.y = __float_as_uint(dinv[base + b] * dinv[c]);
            edge_s[pos] = v;
        }
    }
}

// ---------------------------------------------------------------------------
// Weight prep: W1T [256][512] bf16 (= W1^T), W2T [48][256] bf16 (rows 40..47=0).
// ---------------------------------------------------------------------------

__global__ void prep_weights(const float* __restrict__ W1, const float* __restrict__ W2,
                             ushort* __restrict__ W1T, ushort* __restrict__ W2T) {
    int t = blockIdx.x * blockDim.x + threadIdx.x;
    if (t < F_HID * F_IN) {
        int n = t >> 9, k = t & 511;
        W1T[t] = f2b(W1[(size_t)k * F_HID + n]);
        return;
    }
    int u = t - F_HID * F_IN;
    if (u < F_OUTP * F_HID) {
        int n = u >> 8, k = u & 255;
        W2T[u] = f2b((n < F_OUT) ? W2[(size_t)k * F_OUT + n] : 0.f);
    }
}

// ---------------------------------------------------------------------------
// GEMM1 (MFMA bf16): h[M,256] = x[M,512] @ W1.  BM=64, BN=256, BK=32.
// Output h stored as fp8 e4m3 (256 B/row) for prop1's gathers.
// ---------------------------------------------------------------------------

#define G1_LDK 40

__global__ __launch_bounds__(256) void gemm1_mfma(const float* __restrict__ A,
                                                  const ushort* __restrict__ BT,
                                                  unsigned char* __restrict__ C, int M) {
    __shared__ ushort As[64 * G1_LDK];
    __shared__ ushort Bs[256 * G1_LDK];
    const int tid  = threadIdx.x;
    const int bm   = blockIdx.x * 64;
    const int wave = tid >> 6;
    const int lane = tid & 63;
    const int quad = lane >> 4;
    const int l16  = lane & 15;

    f32x4 acc[4][4] = {};

    const int ar = tid >> 2;
    const int ac = (tid & 3) * 8;

    for (int k0 = 0; k0 < F_IN; k0 += 32) {
        {
            int gr = bm + ar;
            float4 v0 = make_float4(0.f, 0.f, 0.f, 0.f), v1 = v0;
            if (gr < M) {
                const float* ap = A + (size_t)gr * F_IN + k0 + ac;
                v0 = *(const float4*)(ap);
                v1 = *(const float4*)(ap + 4);
            }
            uint4 w;
            w.x = pack2(v0.x, v0.y);
            w.y = pack2(v0.z, v0.w);
            w.z = pack2(v1.x, v1.y);
            w.w = pack2(v1.z, v1.w);
            *(uint4*)&As[ar * G1_LDK + ac] = w;
        }
#pragma unroll
        for (int p = 0; p < 4; ++p) {
            int idx = tid + p * 256;
            int r = idx >> 2;
            int c = (idx & 3) * 8;
            uint4 v = *(const uint4*)(BT + (size_t)r * F_IN + k0 + c);
            *(uint4*)&Bs[r * G1_LDK + c] = v;
        }
        __syncthreads();

        bf16x8 af[4], bfr[4];
#pragma unroll
        for (int mt = 0; mt < 4; ++mt)
            af[mt] = *(bf16x8*)&As[(mt * 16 + l16) * G1_LDK + quad * 8];
#pragma unroll
        for (int nt = 0; nt < 4; ++nt)
            bfr[nt] = *(bf16x8*)&Bs[(wave * 64 + nt * 16 + l16) * G1_LDK + quad * 8];
#pragma unroll
        for (int mt = 0; mt < 4; ++mt)
#pragma unroll
            for (int nt = 0; nt < 4; ++nt)
                acc[mt][nt] = __builtin_amdgcn_mfma_f32_16x16x32_bf16(af[mt], bfr[nt],
                                                                     acc[mt][nt], 0, 0, 0);
        __syncthreads();
    }

#pragma unroll
    for (int mt = 0; mt < 4; ++mt) {
#pragma unroll
        for (int i = 0; i < 4; ++i) {
            int row = bm + mt * 16 + quad * 4 + i;
            if (row < M) {
#pragma unroll
                for (int nt = 0; nt < 4; ++nt) {
                    int col = wave * 64 + nt * 16 + l16;
                    uint pk = (uint)__builtin_amdgcn_cvt_pk_fp8_f32(acc[mt][nt][i], 0.f, 0, false);
                    C[(size_t)row * F_HID + col] = (unsigned char)pk;
                }
            }
        }
    }
}

// ---------------------------------------------------------------------------
// Propagate layer 1 (F=256, fp8) + bias + ReLU. TWO edges per wave gather
// instruction: lanes 0-31 load edge A's row (8 B/lane dwordx2), lanes 32-63
// edge B's. Edge records loaded per-lane as uint2. __launch_bounds__(256,4)
// keeps the in-flight buffers in registers (round-3 spill lesson).
// ---------------------------------------------------------------------------

#define P1E 16   // edges per iteration = 8 aligned pairs

__global__ __launch_bounds__(256, 4) void prop1_kernel(const unsigned char* __restrict__ h,
                                                       const float* __restrict__ b1,
                                                       const float* __restrict__ dinv,
                                                       const int* __restrict__ rowptr,
                                                       const uint2* __restrict__ edge_s,
                                                       ushort* __restrict__ g, int N, int E) {
    int wid  = (blockIdx.x * blockDim.x + threadIdx.x) >> 6;
    int lane = threadIdx.x & 63;
    if (wid >= N) return;
    const uint2* hq = (const uint2*)h;      // row = 32 uint2 slots (256 B)
    const int half = lane >> 5;
    const int slot = lane & 31;
    float di = dinv[wid];
    float sn = (half == 0) ? di * di : 0.f;   // self term counted once (low half)

    float acc[8];
    {
        uint2 sv = hq[(size_t)wid * 32 + slot];
        f32x2 a01 = __builtin_amdgcn_cvt_pk_f32_fp8((int)sv.x, false);
        f32x2 a23 = __builtin_amdgcn_cvt_pk_f32_fp8((int)sv.x, true);
        f32x2 a45 = __builtin_amdgcn_cvt_pk_f32_fp8((int)sv.y, false);
        f32x2 a67 = __builtin_amdgcn_cvt_pk_f32_fp8((int)sv.y, true);
        acc[0] = sn * a01.x; acc[1] = sn * a01.y;
        acc[2] = sn * a23.x; acc[3] = sn * a23.y;
        acc[4] = sn * a45.x; acc[5] = sn * a45.y;
        acc[6] = sn * a67.x; acc[7] = sn * a67.y;
    }

    int e0 = rowptr[wid], e1 = rowptr[wid + 1];
    const int eE = E - 2;                    // last aligned pair start
    for (int e = (e0 & ~1); e < e1; e += P1E) {
        uint2 rc[P1E / 2];                   // per-lane (col, weight) of MY edge
        uint2 v[P1E / 2];
        float w[P1E / 2];
#pragma unroll
        for (int u = 0; u < P1E / 2; ++u) {
            int i0 = min(e + 2 * u, eE);     // even pair base, clamped in-bounds
            rc[u] = edge_s[i0 + half];
        }
#pragma unroll
        for (int u = 0; u < P1E / 2; ++u) {
            int idx = e + 2 * u + half;
            w[u] = (idx >= e0 && idx < e1) ? __uint_as_float(rc[u].y) : 0.f;
            v[u] = hq[(size_t)rc[u].x * 32 + slot];
        }
#pragma unroll
        for (int u = 0; u < P1E / 2; ++u) {
            f32x2 a01 = __builtin_amdgcn_cvt_pk_f32_fp8((int)v[u].x, false);
            f32x2 a23 = __builtin_amdgcn_cvt_pk_f32_fp8((int)v[u].x, true);
            f32x2 a45 = __builtin_amdgcn_cvt_pk_f32_fp8((int)v[u].y, false);
            f32x2 a67 = __builtin_amdgcn_cvt_pk_f32_fp8((int)v[u].y, true);
            acc[0] = fmaf(w[u], a01.x, acc[0]); acc[1] = fmaf(w[u], a01.y, acc[1]);
            acc[2] = fmaf(w[u], a23.x, acc[2]); acc[3] = fmaf(w[u], a23.y, acc[3]);
            acc[4] = fmaf(w[u], a45.x, acc[4]); acc[5] = fmaf(w[u], a45.y, acc[5]);
            acc[6] = fmaf(w[u], a67.x, acc[6]); acc[7] = fmaf(w[u], a67.y, acc[7]);
        }
    }

#pragma unroll
    for (int j = 0; j < 8; ++j) acc[j] += __shfl_xor(acc[j], 32, 64);

    if (half == 0) {
        float4 b0 = ((const float4*)b1)[slot * 2];
        float4 b4 = ((const float4*)b1)[slot * 2 + 1];
        uint4 o;
        o.x = pack2(fmaxf(acc[0] + b0.x, 0.f), fmaxf(acc[1] + b0.y, 0.f));
        o.y = pack2(fmaxf(acc[2] + b0.z, 0.f), fmaxf(acc[3] + b0.w, 0.f));
        o.z = pack2(fmaxf(acc[4] + b4.x, 0.f), fmaxf(acc[5] + b4.y, 0.f));
        o.w = pack2(fmaxf(acc[6] + b4.z, 0.f), fmaxf(acc[7] + b4.w, 0.f));
        ((uint4*)(g + (size_t)wid * F_HID))[slot] = o;
    }
}

// ---------------------------------------------------------------------------
// GEMM2 (MFMA bf16): h2[M,40] = g[M,256] @ W2, K fully LDS-staged.
// h2 rows padded to stride H2_LD=64 ushorts (128 B) for prop2's paired gathers.
// ---------------------------------------------------------------------------

#define G2_LDK 264

__global__ __launch_bounds__(256) void gemm2_mfma(const ushort* __restrict__ G,
                                                  const ushort* __restrict__ BT,
                                                  ushort* __restrict__ H2, int M) {
    __shared__ ushort As[64 * G2_LDK];
    __shared__ ushort Bs[F_OUTP * G2_LDK];
    const int tid  = threadIdx.x;
    const int bm   = blockIdx.x * 64;
    const int wave = tid >> 6;
    const int lane = tid & 63;
    const int quad = lane >> 4;
    const int l16  = lane & 15;

#pragma unroll
    for (int p = 0; p < 8; ++p) {
        int idx = tid + p * 256;
        int r = idx >> 5;
        int c = (idx & 31) * 8;
        uint4 v = make_uint4(0, 0, 0, 0);
        int gr = bm + r;
        if (gr < M) v = *(const uint4*)(G + (size_t)gr * F_HID + c);
        *(uint4*)&As[r * G2_LDK + c] = v;
    }
#pragma unroll
    for (int p = 0; p < 6; ++p) {
        int idx = tid + p * 256;
        int r = idx >> 5;
        int c = (idx & 31) * 8;
        uint4 v = *(const uint4*)(BT + (size_t)r * F_HID + c);
        *(uint4*)&Bs[r * G2_LDK + c] = v;
    }
    __syncthreads();

    f32x4 acc[3] = {};
#pragma unroll
    for (int ks = 0; ks < F_HID / 32; ++ks) {
        bf16x8 a = *(bf16x8*)&As[(wave * 16 + l16) * G2_LDK + ks * 32 + quad * 8];
#pragma unroll
        for (int nt = 0; nt < 3; ++nt) {
            bf16x8 b = *(bf16x8*)&Bs[(nt * 16 + l16) * G2_LDK + ks * 32 + quad * 8];
            acc[nt] = __builtin_amdgcn_mfma_f32_16x16x32_bf16(a, b, acc[nt], 0, 0, 0);
        }
    }

#pragma unroll
    for (int i = 0; i < 4; ++i) {
        int row = bm + wave * 16 + quad * 4 + i;
        if (row < M) {
#pragma unroll
            for (int nt = 0; nt < 3; ++nt) {
                int col = nt * 16 + l16;
                if (col < F_OUT)
                    H2[(size_t)row * H2_LD + col] = f2b(acc[nt][i]);
            }
        }
    }
}

// ---------------------------------------------------------------------------
// Propagate layer 2 (F=40, bf16, 128 B padded rows) + bias + fused
// log_softmax. Same 2-edges-per-gather pairing + per-lane uint2 records as
// prop1. exp-sum from half 0 only (both halves hold full sums post-combine).
// ---------------------------------------------------------------------------

#define P2E 16

__global__ __launch_bounds__(256, 4) void prop2_kernel(const ushort* __restrict__ h2,
                                                       const float* __restrict__ b2,
                                                       const float* __restrict__ dinv,
                                                       const int* __restrict__ rowptr,
                                                       const uint2* __restrict__ edge_s,
                                                       float* __restrict__ out, int N, int E) {
    int wid  = (blockIdx.x * blockDim.x + threadIdx.x) >> 6;
    int lane = threadIdx.x & 63;
    if (wid >= N) return;
    const uint* hq = (const uint*)h2;        // row = 32 uint slots (128 B)
    const int half = lane >> 5;
    const int slot = lane & 31;
    const bool act = slot < (F_OUT / 2);     // features 2*slot, 2*slot+1 valid
    float di = dinv[wid];
    float sn = (half == 0) ? di * di : 0.f;

    float a0, a1;
    {
        uint sv = hq[(size_t)wid * 32 + slot];
        a0 = sn * b2f((ushort)(sv & 0xffffu));
        a1 = sn * b2f((ushort)(sv >> 16));
    }

    int e0 = rowptr[wid], e1 = rowptr[wid + 1];
    const int eE = E - 2;
    for (int e = (e0 & ~1); e < e1; e += P2E) {
        uint2 rc[P2E / 2];
        uint  v[P2E / 2];
        float w[P2E / 2];
#pragma unroll
        for (int u = 0; u < P2E / 2; ++u) {
            int i0 = min(e + 2 * u, eE);
            rc[u] = edge_s[i0 + half];
        }
#pragma unroll
        for (int u = 0; u < P2E / 2; ++u) {
            int idx = e + 2 * u + half;
            w[u] = (idx >= e0 && idx < e1) ? __uint_as_float(rc[u].y) : 0.f;
            v[u] = hq[(size_t)rc[u].x * 32 + slot];
        }
#pragma unroll
        for (int u = 0; u < P2E / 2; ++u) {
            a0 = fmaf(w[u], b2f((ushort)(v[u] & 0xffffu)), a0);
            a1 = fmaf(w[u], b2f((ushort)(v[u] >> 16)), a1);
        }
    }

    a0 += __shfl_xor(a0, 32, 64);
    a1 += __shfl_xor(a1, 32, 64);

    if (act) {                 // exec-masked loads keep b2 (40 floats) in-bounds
        float2 bb = ((const float2*)b2)[slot];
        a0 += bb.x;
        a1 += bb.y;
    }

    float m = act ? fmaxf(a0, a1) : -INFINITY;
#pragma unroll
    for (int o = 32; o; o >>= 1) m = fmaxf(m, __shfl_xor(m, o, 64));
    // exp-sum from half 0 only: both halves hold full sums post-combine
    float ex = (act && half == 0) ? (expf(a0 - m) + expf(a1 - m)) : 0.f;
    float s = ex;
#pragma unroll
    for (int o = 32; o; o >>= 1) s += __shfl_xor(s, o, 64);

    if (half == 0 && act) {
        float ls = m + logf(s);
        size_t base = (size_t)wid * F_OUT + 2 * slot;
        float2 o1; o1.x = a0; o1.y = a1;
        float2 o2; o2.x = a0 - ls; o2.y = a1 - ls;
        *(float2*)(out + base) = o1;
        *(float2*)(out + (size_t)N * F_OUT + base) = o2;
    }
}

// ---------------------------------------------------------------------------
// Launch
// ---------------------------------------------------------------------------

extern "C" void kernel_launch(void* const* d_in, const int* in_sizes, int n_in,
                              void* d_out, int out_size, void* d_ws, size_t ws_size,
                              hipStream_t stream) {
    const float* x  = (const float*)d_in[0];
    const int*   ei = (const int*)d_in[1];
    const float* W1 = (const float*)d_in[2];
    const float* b1 = (const float*)d_in[3];
    const float* W2 = (const float*)d_in[4];
    const float* b2 = (const float*)d_in[5];
    float* out = (float*)d_out;

    const int N = in_sizes[0] / F_IN;
    const int E = in_sizes[1] / 2;
    const int NR = (N + HBINS - 1) / HBINS;
    const int NB = (N + 1023) / 1024;          // scan blocks (<= 1024)

    char* p = (char*)d_ws;
    auto alloc = [&](size_t bytes) -> char* {
        char* q = p;
        p += (bytes + 255) & ~(size_t)255;
        return q;
    };
    int*    cnt_row = (int*)alloc((size_t)N * 4);
    int*    rowptr  = (int*)alloc((size_t)(N + 1) * 4);
    float*  dinv    = (float*)alloc((size_t)N * 4);
    int*    bsum    = (int*)alloc((size_t)1024 * 4);
    uint2*  edge_s  = (uint2*)alloc((size_t)E * 8);
    int*    part    = (int*)alloc((size_t)2 * NR * HSLICES * HBINS * 4);
    int*    offs    = (int*)alloc((size_t)NR * HSLICES * HBINS * 4);
    ushort* W1T     = (ushort*)alloc((size_t)F_HID * F_IN * 2);
    ushort* W2T     = (ushort*)alloc((size_t)F_OUTP * F_HID * 2);
    unsigned char* h = (unsigned char*)alloc((size_t)N * F_HID);   // fp8 e4m3
    ushort* g       = (ushort*)alloc((size_t)N * F_HID * 2);
    ushort* h2      = (ushort*)alloc((size_t)N * H2_LD * 2);       // padded rows

    dim3 hgrid(HSLICES, NR, 2);
    hist_kernel<<<hgrid, 1024, 0, stream>>>(ei, part, E, NR);
    hist_reduce<<<(2 * N + 255) / 256, 256, 0, stream>>>(part, cnt_row, dinv, N, NR);

    scan_part<<<NB, 1024, 0, stream>>>(cnt_row, bsum, N);
    scan_bsum<<<1, 1024, 0, stream>>>(bsum, rowptr, NB, N);
    scan_write<<<NB, 1024, 0, stream>>>(cnt_row, bsum, rowptr, N);

    slice_scan<<<(NR * HBINS + 255) / 256, 256, 0, stream>>>(part, rowptr, offs, N, NR);

    dim3 pgrid(HSLICES, NR);
    place_kernel<<<pgrid, 1024, 0, stream>>>(ei, dinv, offs, edge_s, E, NR);

    int prep_total = F_HID * F_IN + F_OUTP * F_HID;
    prep_weights<<<(prep_total + 255) / 256, 256, 0, stream>>>(W1, W2, W1T, W2T);

    gemm1_mfma<<<(N + 63) / 64, 256, 0, stream>>>(x, W1T, h, N);
    prop1_kernel<<<(N + 3) / 4, 256, 0, stream>>>(h, b1, dinv, rowptr, edge_s, g, N, E);
    gemm2_mfma<<<(N + 63) / 64, 256, 0, stream>>>(g, W2T, h2, N);
    prop2_kernel<<<(N + 3) / 4, 256, 0, stream>>>(h2, b2, dinv, rowptr, edge_s, out, N, E);
}

// Round 6
// 699.709 us; speedup vs baseline: 2.1415x; 1.0230x over previous
//
#include <hip/hip_runtime.h>
#include <cstdint>
#include <cstddef>

#define F_IN  512
#define F_HID 256
#define F_OUT 40
#define F_OUTP 48    // padded to 3x16 MFMA tiles
#define H2_LD 64     // h2 row stride in ushorts (128 B, 2 lines, aligned)

#define HBINS 16384        // 64 KB LDS histogram bins
#define HSLICES 36         // edge slices for hist/place passes

typedef short  bf16x8 __attribute__((ext_vector_type(8)));
typedef float  f32x4  __attribute__((ext_vector_type(4)));
typedef float  f32x2  __attribute__((ext_vector_type(2)));

__device__ __forceinline__ ushort f2b(float f) {   // fp32 -> bf16 RNE
    uint u = __float_as_uint(f);
    return (ushort)((u + 0x7FFFu + ((u >> 16) & 1u)) >> 16);
}
__device__ __forceinline__ uint pack2(float a, float b) {
    return (uint)f2b(a) | ((uint)f2b(b) << 16);
}
__device__ __forceinline__ float b2f(ushort u) {
    return __uint_as_float(((uint)u) << 16);
}

// ---------------------------------------------------------------------------
// Degree histogram WITHOUT global atomics: block (slice s, range r, array a)
// scans its edge slice, counts indices in [r*HBINS, r*HBINS+HBINS) into an LDS
// histogram, writes the 64 KB partial to scratch non-atomically.
// ---------------------------------------------------------------------------

__global__ __launch_bounds__(1024) void hist_kernel(const int* __restrict__ ei,
                                                    int* __restrict__ part,
                                                    int E, int NR) {
    __shared__ int hist[HBINS];
    const int tid = threadIdx.x;
    const int s = blockIdx.x;
    const int r = blockIdx.y;
    const int a = blockIdx.z;
    const int* src = ei + (size_t)a * E;   // a=0: row, a=1: col
    const uint base = (uint)r * HBINS;

    for (int i = tid; i < HBINS; i += 1024) hist[i] = 0;
    __syncthreads();

    int elen  = (E + HSLICES - 1) / HSLICES;
    int start = s * elen;
    int end   = min(start + elen, E);
    for (int i = start + tid; i < end; i += 1024) {
        uint b = (uint)src[i] - base;
        if (b < HBINS) atomicAdd(&hist[b], 1);
    }
    __syncthreads();

    int* dst = part + ((size_t)(a * NR + r) * HSLICES + s) * HBINS;
    for (int i = tid; i < HBINS; i += 1024) dst[i] = hist[i];
}

// Sum the HSLICES partials per (array, node). a=0 -> cnt_row; a=1 -> dinv.
__global__ void hist_reduce(const int* __restrict__ part,
                            int* __restrict__ cnt_row,
                            float* __restrict__ dinv, int N, int NR) {
    int t = blockIdx.x * blockDim.x + threadIdx.x;
    if (t >= 2 * N) return;
    int a = (t >= N) ? 1 : 0;
    int i = t - a * N;
    int r = i >> 14;             // / HBINS
    int bin = i & (HBINS - 1);
    const int* p = part + ((size_t)(a * NR + r) * HSLICES) * HBINS + bin;
    int sum = 0;
#pragma unroll 4
    for (int s = 0; s < HSLICES; ++s) sum += p[(size_t)s * HBINS];
    if (a == 0) cnt_row[i] = sum;
    else        dinv[i] = rsqrtf((float)(sum + 1));
}

// ---------------------------------------------------------------------------
// Multi-block exclusive scan of cnt_row -> rowptr[N+1]: 3 parallel phases.
// ---------------------------------------------------------------------------

// Phase 1: block b writes sum of cnt[b*1024 .. b*1024+1023] to bsum[b].
__global__ __launch_bounds__(1024) void scan_part(const int* __restrict__ cnt,
                                                  int* __restrict__ bsum, int N) {
    __shared__ int wred[16];
    int tid = threadIdx.x;
    int i = blockIdx.x * 1024 + tid;
    int v = (i < N) ? cnt[i] : 0;
#pragma unroll
    for (int o = 32; o; o >>= 1) v += __shfl_xor(v, o, 64);
    int wid = tid >> 6, lane = tid & 63;
    if (lane == 0) wred[wid] = v;
    __syncthreads();
    if (tid < 16) {
        int s = wred[tid];
#pragma unroll
        for (int o = 8; o; o >>= 1) s += __shfl_xor(s, o, 64);
        if (tid == 0) bsum[blockIdx.x] = s;
    }
}

// Phase 2: single block exclusive-scans bsum[0..NB) in LDS (NB <= 1024),
// writes rowptr[N] = grand total.
__global__ __launch_bounds__(1024) void scan_bsum(int* __restrict__ bsum,
                                                  int* __restrict__ rowptr,
                                                  int NB, int N) {
    __shared__ int s[1024];
    int tid = threadIdx.x;
    s[tid] = (tid < NB) ? bsum[tid] : 0;
    __syncthreads();
    for (int off = 1; off < 1024; off <<= 1) {
        int v = (tid >= off) ? s[tid - off] : 0;
        __syncthreads();
        s[tid] += v;
        __syncthreads();
    }
    if (tid < NB) bsum[tid] = (tid > 0) ? s[tid - 1] : 0;
    if (tid == 0) rowptr[N] = s[1023];
}

// Phase 3: block b re-reads its chunk, block-wide exclusive scan + bsum[b].
__global__ __launch_bounds__(1024) void scan_write(const int* __restrict__ cnt,
                                                   const int* __restrict__ bsum,
                                                   int* __restrict__ rowptr, int N) {
    __shared__ int wsum[16];
    int tid = threadIdx.x;
    int wid = tid >> 6, lane = tid & 63;
    int i = blockIdx.x * 1024 + tid;
    int v = (i < N) ? cnt[i] : 0;
    int incl = v;
#pragma unroll
    for (int o = 1; o < 64; o <<= 1) {
        int t = __shfl_up(incl, o, 64);
        if (lane >= o) incl += t;
    }
    if (lane == 63) wsum[wid] = incl;
    __syncthreads();
    if (tid < 16) {
        int s = wsum[tid];
#pragma unroll
        for (int o = 1; o < 16; o <<= 1) {
            int t = __shfl_up(s, o, 64);
            if (tid >= o) s += t;
        }
        wsum[tid] = s;   // inclusive scan of wave sums
    }
    __syncthreads();
    int base = bsum[blockIdx.x] + ((wid > 0) ? wsum[wid - 1] : 0);
    if (i < N) rowptr[i] = base + incl - v;   // exclusive
}

// ---------------------------------------------------------------------------
// offs[r][s][bin] = rowptr[node] + sum_{s'<s} part[a=0][r][s'][bin].
// ---------------------------------------------------------------------------

__global__ void slice_scan(const int* __restrict__ part,
                           const int* __restrict__ rowptr,
                           int* __restrict__ offs, int N, int NR) {
    int i = blockIdx.x * blockDim.x + threadIdx.x;
    if (i >= NR * HBINS) return;
    int r = i >> 14;
    int bin = i & (HBINS - 1);
    int acc = (i < N) ? rowptr[i] : 0;
    const int* p = part + ((size_t)r * HSLICES) * HBINS + bin;   // a=0 block
    int* o = offs + ((size_t)r * HSLICES) * HBINS + bin;
    for (int s = 0; s < HSLICES; ++s) {
        o[(size_t)s * HBINS] = acc;
        acc += p[(size_t)s * HBINS];
    }
}

// ---------------------------------------------------------------------------
// CSR placement with LDS cursors only (no global atomics). Block (s, r) loads
// its offset slab into LDS, re-scans its edge slice, places in-range edges.
// ---------------------------------------------------------------------------

__global__ __launch_bounds__(1024) void place_kernel(const int* __restrict__ ei,
                                                     const float* __restrict__ dinv,
                                                     const int* __restrict__ offs,
                                                     uint2* __restrict__ edge_s,
                                                     int E, int NR) {
    __shared__ int cur[HBINS];
    const int tid = threadIdx.x;
    const int s = blockIdx.x;
    const int r = blockIdx.y;
    const int* row = ei;
    const int* col = ei + E;
    const uint base = (uint)r * HBINS;
    const int* oslab = offs + ((size_t)r * HSLICES + s) * HBINS;

    for (int i = tid; i < HBINS; i += 1024) cur[i] = oslab[i];
    __syncthreads();

    int elen  = (E + HSLICES - 1) / HSLICES;
    int start = s * elen;
    int end   = min(start + elen, E);
    for (int i = start + tid; i < end; i += 1024) {
        uint b = (uint)row[i] - base;
        if (b < HBINS) {
            int pos = atomicAdd(&cur[b], 1);
            int c = col[i];
            uint2 v;
            v.x = (uint)c;
            v.y = __float_as_uint(dinv[base + b] * dinv[c]);
            edge_s[pos] = v;
        }
    }
}

// ---------------------------------------------------------------------------
// Weight prep: W1T [256][512] bf16 (= W1^T), W2T [48][256] bf16 (rows 40..47=0).
// ---------------------------------------------------------------------------

__global__ void prep_weights(const float* __restrict__ W1, const float* __restrict__ W2,
                             ushort* __restrict__ W1T, ushort* __restrict__ W2T) {
    int t = blockIdx.x * blockDim.x + threadIdx.x;
    if (t < F_HID * F_IN) {
        int n = t >> 9, k = t & 511;
        W1T[t] = f2b(W1[(size_t)k * F_HID + n]);
        return;
    }
    int u = t - F_HID * F_IN;
    if (u < F_OUTP * F_HID) {
        int n = u >> 8, k = u & 255;
        W2T[u] = f2b((n < F_OUT) ? W2[(size_t)k * F_OUT + n] : 0.f);
    }
}

// ---------------------------------------------------------------------------
// GEMM1 (MFMA bf16): h[M,256] = x[M,512] @ W1.  BM=64, BN=256, BK=32.
// Output h stored as fp8 e4m3 (256 B/row) for prop1's gathers.
// ---------------------------------------------------------------------------

#define G1_LDK 40

__global__ __launch_bounds__(256) void gemm1_mfma(const float* __restrict__ A,
                                                  const ushort* __restrict__ BT,
                                                  unsigned char* __restrict__ C, int M) {
    __shared__ ushort As[64 * G1_LDK];
    __shared__ ushort Bs[256 * G1_LDK];
    const int tid  = threadIdx.x;
    const int bm   = blockIdx.x * 64;
    const int wave = tid >> 6;
    const int lane = tid & 63;
    const int quad = lane >> 4;
    const int l16  = lane & 15;

    f32x4 acc[4][4] = {};

    const int ar = tid >> 2;
    const int ac = (tid & 3) * 8;

    for (int k0 = 0; k0 < F_IN; k0 += 32) {
        {
            int gr = bm + ar;
            float4 v0 = make_float4(0.f, 0.f, 0.f, 0.f), v1 = v0;
            if (gr < M) {
                const float* ap = A + (size_t)gr * F_IN + k0 + ac;
                v0 = *(const float4*)(ap);
                v1 = *(const float4*)(ap + 4);
            }
            uint4 w;
            w.x = pack2(v0.x, v0.y);
            w.y = pack2(v0.z, v0.w);
            w.z = pack2(v1.x, v1.y);
            w.w = pack2(v1.z, v1.w);
            *(uint4*)&As[ar * G1_LDK + ac] = w;
        }
#pragma unroll
        for (int p = 0; p < 4; ++p) {
            int idx = tid + p * 256;
            int r = idx >> 2;
            int c = (idx & 3) * 8;
            uint4 v = *(const uint4*)(BT + (size_t)r * F_IN + k0 + c);
            *(uint4*)&Bs[r * G1_LDK + c] = v;
        }
        __syncthreads();

        bf16x8 af[4], bfr[4];
#pragma unroll
        for (int mt = 0; mt < 4; ++mt)
            af[mt] = *(bf16x8*)&As[(mt * 16 + l16) * G1_LDK + quad * 8];
#pragma unroll
        for (int nt = 0; nt < 4; ++nt)
            bfr[nt] = *(bf16x8*)&Bs[(wave * 64 + nt * 16 + l16) * G1_LDK + quad * 8];
#pragma unroll
        for (int mt = 0; mt < 4; ++mt)
#pragma unroll
            for (int nt = 0; nt < 4; ++nt)
                acc[mt][nt] = __builtin_amdgcn_mfma_f32_16x16x32_bf16(af[mt], bfr[nt],
                                                                     acc[mt][nt], 0, 0, 0);
        __syncthreads();
    }

#pragma unroll
    for (int mt = 0; mt < 4; ++mt) {
#pragma unroll
        for (int i = 0; i < 4; ++i) {
            int row = bm + mt * 16 + quad * 4 + i;
            if (row < M) {
#pragma unroll
                for (int nt = 0; nt < 4; ++nt) {
                    int col = wave * 64 + nt * 16 + l16;
                    uint pk = (uint)__builtin_amdgcn_cvt_pk_fp8_f32(acc[mt][nt][i], 0.f, 0, false);
                    C[(size_t)row * F_HID + col] = (unsigned char)pk;
                }
            }
        }
    }
}

// ---------------------------------------------------------------------------
// Propagate layer 1 (F=256, fp8) + bias + ReLU. FOUR edges per wave gather
// instruction: quad q (lanes 16q..16q+15) loads edge q's row at 16 B/lane
// (dwordx4). Per-lane record load covers 4 records (uint2 at pairbase+quad).
// 0.5 vmem instr/edge vs round-5's 1.0 — the 16 cyc/instr issue cost was the
// dominant term of the validated cost model. Cross-quad combine: shfl 16+32.
// ---------------------------------------------------------------------------

#define P1U 4    // quad-iterations in flight: 16 edges per loop pass

__global__ __launch_bounds__(256, 4) void prop1_kernel(const unsigned char* __restrict__ h,
                                                       const float* __restrict__ b1,
                                                       const float* __restrict__ dinv,
                                                       const int* __restrict__ rowptr,
                                                       const uint2* __restrict__ edge_s,
                                                       ushort* __restrict__ g, int N, int E) {
    int wid  = (blockIdx.x * blockDim.x + threadIdx.x) >> 6;
    int lane = threadIdx.x & 63;
    if (wid >= N) return;
    const uint4* hq4 = (const uint4*)h;     // row = 16 uint4 slots (256 B)
    const int quad = lane >> 4;             // which edge of the 4-group
    const int l16  = lane & 15;             // 16-feature slice within the row
    float di = dinv[wid];
    float sn = (quad == 0) ? di * di : 0.f; // self term counted once

    float acc[16];
    {
        uint4 sv = hq4[(size_t)wid * 16 + l16];
        f32x2 p01 = __builtin_amdgcn_cvt_pk_f32_fp8((int)sv.x, false);
        f32x2 p23 = __builtin_amdgcn_cvt_pk_f32_fp8((int)sv.x, true);
        f32x2 p45 = __builtin_amdgcn_cvt_pk_f32_fp8((int)sv.y, false);
        f32x2 p67 = __builtin_amdgcn_cvt_pk_f32_fp8((int)sv.y, true);
        f32x2 p89 = __builtin_amdgcn_cvt_pk_f32_fp8((int)sv.z, false);
        f32x2 pab = __builtin_amdgcn_cvt_pk_f32_fp8((int)sv.z, true);
        f32x2 pcd = __builtin_amdgcn_cvt_pk_f32_fp8((int)sv.w, false);
        f32x2 pef = __builtin_amdgcn_cvt_pk_f32_fp8((int)sv.w, true);
        acc[0]  = sn * p01.x; acc[1]  = sn * p01.y;
        acc[2]  = sn * p23.x; acc[3]  = sn * p23.y;
        acc[4]  = sn * p45.x; acc[5]  = sn * p45.y;
        acc[6]  = sn * p67.x; acc[7]  = sn * p67.y;
        acc[8]  = sn * p89.x; acc[9]  = sn * p89.y;
        acc[10] = sn * pab.x; acc[11] = sn * pab.y;
        acc[12] = sn * pcd.x; acc[13] = sn * pcd.y;
        acc[14] = sn * pef.x; acc[15] = sn * pef.y;
    }

    int e0 = rowptr[wid], e1 = rowptr[wid + 1];
    const int eE = E - 4;                    // last 4-group base kept in-bounds
    for (int e = (e0 & ~3); e < e1; e += 4 * P1U) {
        uint2 rc[P1U];                       // my quad's (col, weight)
        uint4 v[P1U];
        float w[P1U];
#pragma unroll
        for (int u = 0; u < P1U; ++u) {
            int i0 = min(e + 4 * u, eE);
            rc[u] = edge_s[i0 + quad];
        }
#pragma unroll
        for (int u = 0; u < P1U; ++u) {
            int idx = e + 4 * u + quad;
            w[u] = (idx >= e0 && idx < e1) ? __uint_as_float(rc[u].y) : 0.f;
            v[u] = hq4[(size_t)rc[u].x * 16 + l16];
        }
#pragma unroll
        for (int u = 0; u < P1U; ++u) {
            f32x2 p01 = __builtin_amdgcn_cvt_pk_f32_fp8((int)v[u].x, false);
            f32x2 p23 = __builtin_amdgcn_cvt_pk_f32_fp8((int)v[u].x, true);
            f32x2 p45 = __builtin_amdgcn_cvt_pk_f32_fp8((int)v[u].y, false);
            f32x2 p67 = __builtin_amdgcn_cvt_pk_f32_fp8((int)v[u].y, true);
            f32x2 p89 = __builtin_amdgcn_cvt_pk_f32_fp8((int)v[u].z, false);
            f32x2 pab = __builtin_amdgcn_cvt_pk_f32_fp8((int)v[u].z, true);
            f32x2 pcd = __builtin_amdgcn_cvt_pk_f32_fp8((int)v[u].w, false);
            f32x2 pef = __builtin_amdgcn_cvt_pk_f32_fp8((int)v[u].w, true);
            acc[0]  = fmaf(w[u], p01.x, acc[0]);  acc[1]  = fmaf(w[u], p01.y, acc[1]);
            acc[2]  = fmaf(w[u], p23.x, acc[2]);  acc[3]  = fmaf(w[u], p23.y, acc[3]);
            acc[4]  = fmaf(w[u], p45.x, acc[4]);  acc[5]  = fmaf(w[u], p45.y, acc[5]);
            acc[6]  = fmaf(w[u], p67.x, acc[6]);  acc[7]  = fmaf(w[u], p67.y, acc[7]);
            acc[8]  = fmaf(w[u], p89.x, acc[8]);  acc[9]  = fmaf(w[u], p89.y, acc[9]);
            acc[10] = fmaf(w[u], pab.x, acc[10]); acc[11] = fmaf(w[u], pab.y, acc[11]);
            acc[12] = fmaf(w[u], pcd.x, acc[12]); acc[13] = fmaf(w[u], pcd.y, acc[13]);
            acc[14] = fmaf(w[u], pef.x, acc[14]); acc[15] = fmaf(w[u], pef.y, acc[15]);
        }
    }

#pragma unroll
    for (int j = 0; j < 16; ++j) {
        acc[j] += __shfl_xor(acc[j], 16, 64);
        acc[j] += __shfl_xor(acc[j], 32, 64);
    }

    if (quad == 0) {
        const float4* bb = (const float4*)b1;
        float4 b0 = bb[l16 * 4 + 0];
        float4 b4 = bb[l16 * 4 + 1];
        float4 b8 = bb[l16 * 4 + 2];
        float4 bc = bb[l16 * 4 + 3];
        uint4 o0, o1;
        o0.x = pack2(fmaxf(acc[0]  + b0.x, 0.f), fmaxf(acc[1]  + b0.y, 0.f));
        o0.y = pack2(fmaxf(acc[2]  + b0.z, 0.f), fmaxf(acc[3]  + b0.w, 0.f));
        o0.z = pack2(fmaxf(acc[4]  + b4.x, 0.f), fmaxf(acc[5]  + b4.y, 0.f));
        o0.w = pack2(fmaxf(acc[6]  + b4.z, 0.f), fmaxf(acc[7]  + b4.w, 0.f));
        o1.x = pack2(fmaxf(acc[8]  + b8.x, 0.f), fmaxf(acc[9]  + b8.y, 0.f));
        o1.y = pack2(fmaxf(acc[10] + b8.z, 0.f), fmaxf(acc[11] + b8.w, 0.f));
        o1.z = pack2(fmaxf(acc[12] + bc.x, 0.f), fmaxf(acc[13] + bc.y, 0.f));
        o1.w = pack2(fmaxf(acc[14] + bc.z, 0.f), fmaxf(acc[15] + bc.w, 0.f));
        uint4* gq = (uint4*)(g + (size_t)wid * F_HID);
        gq[l16 * 2]     = o0;
        gq[l16 * 2 + 1] = o1;
    }
}

// ---------------------------------------------------------------------------
// GEMM2 (MFMA bf16): h2[M,40] = g[M,256] @ W2, K fully LDS-staged.
// h2 rows padded to stride H2_LD=64 ushorts (128 B) for prop2's quad gathers.
// ---------------------------------------------------------------------------

#define G2_LDK 264

__global__ __launch_bounds__(256) void gemm2_mfma(const ushort* __restrict__ G,
                                                  const ushort* __restrict__ BT,
                                                  ushort* __restrict__ H2, int M) {
    __shared__ ushort As[64 * G2_LDK];
    __shared__ ushort Bs[F_OUTP * G2_LDK];
    const int tid  = threadIdx.x;
    const int bm   = blockIdx.x * 64;
    const int wave = tid >> 6;
    const int lane = tid & 63;
    const int quad = lane >> 4;
    const int l16  = lane & 15;

#pragma unroll
    for (int p = 0; p < 8; ++p) {
        int idx = tid + p * 256;
        int r = idx >> 5;
        int c = (idx & 31) * 8;
        uint4 v = make_uint4(0, 0, 0, 0);
        int gr = bm + r;
        if (gr < M) v = *(const uint4*)(G + (size_t)gr * F_HID + c);
        *(uint4*)&As[r * G2_LDK + c] = v;
    }
#pragma unroll
    for (int p = 0; p < 6; ++p) {
        int idx = tid + p * 256;
        int r = idx >> 5;
        int c = (idx & 31) * 8;
        uint4 v = *(const uint4*)(BT + (size_t)r * F_HID + c);
        *(uint4*)&Bs[r * G2_LDK + c] = v;
    }
    __syncthreads();

    f32x4 acc[3] = {};
#pragma unroll
    for (int ks = 0; ks < F_HID / 32; ++ks) {
        bf16x8 a = *(bf16x8*)&As[(wave * 16 + l16) * G2_LDK + ks * 32 + quad * 8];
#pragma unroll
        for (int nt = 0; nt < 3; ++nt) {
            bf16x8 b = *(bf16x8*)&Bs[(nt * 16 + l16) * G2_LDK + ks * 32 + quad * 8];
            acc[nt] = __builtin_amdgcn_mfma_f32_16x16x32_bf16(a, b, acc[nt], 0, 0, 0);
        }
    }

#pragma unroll
    for (int i = 0; i < 4; ++i) {
        int row = bm + wave * 16 + quad * 4 + i;
        if (row < M) {
#pragma unroll
            for (int nt = 0; nt < 3; ++nt) {
                int col = nt * 16 + l16;
                if (col < F_OUT)
                    H2[(size_t)row * H2_LD + col] = f2b(acc[nt][i]);
            }
        }
    }
}

// ---------------------------------------------------------------------------
// Propagate layer 2 (F=40, bf16, 128 B padded rows) + bias + fused
// log_softmax. 4 edges per gather: quad q loads edge q's row at 8 B/lane
// (uint2 = 4 bf16 features). Lanes l16>=10 read pad, fully masked.
// Cross-quad combine shfl 16+32; epilogue (bias/softmax-sum/write) is
// quad-0-only to avoid the round-2 duplicate-denominator bug.
// ---------------------------------------------------------------------------

#define P2U 4    // 16 edges per loop pass

__global__ __launch_bounds__(256, 4) void prop2_kernel(const ushort* __restrict__ h2,
                                                       const float* __restrict__ b2,
                                                       const float* __restrict__ dinv,
                                                       const int* __restrict__ rowptr,
                                                       const uint2* __restrict__ edge_s,
                                                       float* __restrict__ out, int N, int E) {
    int wid  = (blockIdx.x * blockDim.x + threadIdx.x) >> 6;
    int lane = threadIdx.x & 63;
    if (wid >= N) return;
    const uint2* hq2 = (const uint2*)h2;     // row = 16 uint2 slots (128 B)
    const int quad = lane >> 4;
    const int l16  = lane & 15;
    const bool act = l16 < (F_OUT / 4);      // features 4*l16..4*l16+3 valid
    float di = dinv[wid];
    float sn = (quad == 0) ? di * di : 0.f;

    float a0, a1, a2, a3;
    {
        uint2 sv = hq2[(size_t)wid * 16 + l16];
        a0 = sn * b2f((ushort)(sv.x & 0xffffu));
        a1 = sn * b2f((ushort)(sv.x >> 16));
        a2 = sn * b2f((ushort)(sv.y & 0xffffu));
        a3 = sn * b2f((ushort)(sv.y >> 16));
    }

    int e0 = rowptr[wid], e1 = rowptr[wid + 1];
    const int eE = E - 4;
    for (int e = (e0 & ~3); e < e1; e += 4 * P2U) {
        uint2 rc[P2U];
        uint2 v[P2U];
        float w[P2U];
#pragma unroll
        for (int u = 0; u < P2U; ++u) {
            int i0 = min(e + 4 * u, eE);
            rc[u] = edge_s[i0 + quad];
        }
#pragma unroll
        for (int u = 0; u < P2U; ++u) {
            int idx = e + 4 * u + quad;
            w[u] = (idx >= e0 && idx < e1) ? __uint_as_float(rc[u].y) : 0.f;
            v[u] = hq2[(size_t)rc[u].x * 16 + l16];
        }
#pragma unroll
        for (int u = 0; u < P2U; ++u) {
            a0 = fmaf(w[u], b2f((ushort)(v[u].x & 0xffffu)), a0);
            a1 = fmaf(w[u], b2f((ushort)(v[u].x >> 16)), a1);
            a2 = fmaf(w[u], b2f((ushort)(v[u].y & 0xffffu)), a2);
            a3 = fmaf(w[u], b2f((ushort)(v[u].y >> 16)), a3);
        }
    }

    a0 += __shfl_xor(a0, 16, 64); a0 += __shfl_xor(a0, 32, 64);
    a1 += __shfl_xor(a1, 16, 64); a1 += __shfl_xor(a1, 32, 64);
    a2 += __shfl_xor(a2, 16, 64); a2 += __shfl_xor(a2, 32, 64);
    a3 += __shfl_xor(a3, 16, 64); a3 += __shfl_xor(a3, 32, 64);

    const bool q0 = (quad == 0);
    if (q0 && act) {               // exec-masked: b2 has exactly 10 float4s
        float4 bb = ((const float4*)b2)[l16];
        a0 += bb.x; a1 += bb.y; a2 += bb.z; a3 += bb.w;
    }

    float m = (q0 && act) ? fmaxf(fmaxf(a0, a1), fmaxf(a2, a3)) : -INFINITY;
#pragma unroll
    for (int o = 32; o; o >>= 1) m = fmaxf(m, __shfl_xor(m, o, 64));
    // exp-sum strictly from quad 0's active lanes (all quads hold full sums)
    float ex = (q0 && act) ? (expf(a0 - m) + expf(a1 - m) + expf(a2 - m) + expf(a3 - m)) : 0.f;
    float s = ex;
#pragma unroll
    for (int o = 32; o; o >>= 1) s += __shfl_xor(s, o, 64);

    if (q0 && act) {
        float ls = m + logf(s);
        size_t base = (size_t)wid * F_OUT + 4 * l16;
        float4 o1; o1.x = a0; o1.y = a1; o1.z = a2; o1.w = a3;
        float4 o2; o2.x = a0 - ls; o2.y = a1 - ls; o2.z = a2 - ls; o2.w = a3 - ls;
        *(float4*)(out + base) = o1;
        *(float4*)(out + (size_t)N * F_OUT + base) = o2;
    }
}

// ---------------------------------------------------------------------------
// Launch
// ---------------------------------------------------------------------------

extern "C" void kernel_launch(void* const* d_in, const int* in_sizes, int n_in,
                              void* d_out, int out_size, void* d_ws, size_t ws_size,
                              hipStream_t stream) {
    const float* x  = (const float*)d_in[0];
    const int*   ei = (const int*)d_in[1];
    const float* W1 = (const float*)d_in[2];
    const float* b1 = (const float*)d_in[3];
    const float* W2 = (const float*)d_in[4];
    const float* b2 = (const float*)d_in[5];
    float* out = (float*)d_out;

    const int N = in_sizes[0] / F_IN;
    const int E = in_sizes[1] / 2;
    const int NR = (N + HBINS - 1) / HBINS;
    const int NB = (N + 1023) / 1024;          // scan blocks (<= 1024)

    char* p = (char*)d_ws;
    auto alloc = [&](size_t bytes) -> char* {
        char* q = p;
        p += (bytes + 255) & ~(size_t)255;
        return q;
    };
    int*    cnt_row = (int*)alloc((size_t)N * 4);
    int*    rowptr  = (int*)alloc((size_t)(N + 1) * 4);
    float*  dinv    = (float*)alloc((size_t)N * 4);
    int*    bsum    = (int*)alloc((size_t)1024 * 4);
    uint2*  edge_s  = (uint2*)alloc((size_t)E * 8);
    int*    part    = (int*)alloc((size_t)2 * NR * HSLICES * HBINS * 4);
    int*    offs    = (int*)alloc((size_t)NR * HSLICES * HBINS * 4);
    ushort* W1T     = (ushort*)alloc((size_t)F_HID * F_IN * 2);
    ushort* W2T     = (ushort*)alloc((size_t)F_OUTP * F_HID * 2);
    unsigned char* h = (unsigned char*)alloc((size_t)N * F_HID);   // fp8 e4m3
    ushort* g       = (ushort*)alloc((size_t)N * F_HID * 2);
    ushort* h2      = (ushort*)alloc((size_t)N * H2_LD * 2);       // padded rows

    dim3 hgrid(HSLICES, NR, 2);
    hist_kernel<<<hgrid, 1024, 0, stream>>>(ei, part, E, NR);
    hist_reduce<<<(2 * N + 255) / 256, 256, 0, stream>>>(part, cnt_row, dinv, N, NR);

    scan_part<<<NB, 1024, 0, stream>>>(cnt_row, bsum, N);
    scan_bsum<<<1, 1024, 0, stream>>>(bsum, rowptr, NB, N);
    scan_write<<<NB, 1024, 0, stream>>>(cnt_row, bsum, rowptr, N);

    slice_scan<<<(NR * HBINS + 255) / 256, 256, 0, stream>>>(part, rowptr, offs, N, NR);

    dim3 pgrid(HSLICES, NR);
    place_kernel<<<pgrid, 1024, 0, stream>>>(ei, dinv, offs, edge_s, E, NR);

    int prep_total = F_HID * F_IN + F_OUTP * F_HID;
    prep_weights<<<(prep_total + 255) / 256, 256, 0, stream>>>(W1, W2, W1T, W2T);

    gemm1_mfma<<<(N + 63) / 64, 256, 0, stream>>>(x, W1T, h, N);
    prop1_kernel<<<(N + 3) / 4, 256, 0, stream>>>(h, b1, dinv, rowptr, edge_s, g, N, E);
    gemm2_mfma<<<(N + 63) / 64, 256, 0, stream>>>(g, W2T, h2, N);
    prop2_kernel<<<(N + 3) / 4, 256, 0, stream>>>(h2, b2, dinv, rowptr, edge_s, out, N, E);
}